// Round 15
// baseline (453.988 us; speedup 1.0000x reference)
//
#include <hip/hip_runtime.h>
#include <hip/hip_bf16.h>
#include <stdint.h>

#define T_TOK 4096
#define H_DIM 1024
#define F_DIM 2816
#define E_NUM 8

typedef __attribute__((ext_vector_type(8))) __bf16 bf16x8;
typedef __attribute__((ext_vector_type(4))) float floatx4;
typedef __attribute__((ext_vector_type(4))) unsigned int uintx4;
typedef __attribute__((address_space(3))) char lds_char;
typedef __attribute__((address_space(1))) const char glb_char;

// async 16B global->LDS (dest = wave-uniform base + lane*16)
__device__ __forceinline__ void gload16(const void* g, void* l) {
  __builtin_amdgcn_global_load_lds((glb_char*)g, (lds_char*)l, 16, 0, 0);
}

// round-to-nearest-even fp32 -> bf16, packed 2-at-a-time
__device__ __forceinline__ unsigned pack2bf16(float a, float b) {
  unsigned ua = __builtin_bit_cast(unsigned, a);
  unsigned ub = __builtin_bit_cast(unsigned, b);
  ua += 0x7fffu + ((ua >> 16) & 1u);
  ub += 0x7fffu + ((ub >> 16) & 1u);
  return (ua >> 16) | (ub & 0xffff0000u);
}

__device__ __forceinline__ float b2f(unsigned short u) {
  unsigned v = ((unsigned)u) << 16;
  return __builtin_bit_cast(float, v);
}

// XOR swizzle for [row][64 bf16] LDS tiles (128 B rows): proven 0-conflict.
__device__ __forceinline__ int swz(int row, int colb) {
  return (row * 128 + colb) ^ ((row & 7) << 4);
}

// inline exclusive-prefix of counts[0..7] below expert e (branchless, no array)
__device__ __forceinline__ int prefix_off(const int* __restrict__ counts,
                                          int e) {
  int o = 0;
#pragma unroll
  for (int i = 0; i < E_NUM; ++i) o += (i < e) ? counts[i] : 0;
  return o;
}

// ---------------- convert (grid-stride, nontemporal stores) -----------------
// Flat 32B-chunk space: [0,W13C) interleaved w13 -> wB (dst linear in c);
// [W13C,TOTC) flat w2 -> w2b. nt-stores keep L3 for the fp32 source reads.
#define W13C    (E_NUM * 2 * F_DIM * (H_DIM / 8))      // 5,767,168
#define W2C     (E_NUM * F_DIM * H_DIM / 8)            // 2,883,584
#define TOTC    (W13C + W2C)                           // 8,650,752
__global__ __launch_bounds__(256) void convert_all(
    const float* __restrict__ w1, const float* __restrict__ w3,
    const float* __restrict__ w2f, __hip_bfloat16* __restrict__ wB,
    __hip_bfloat16* __restrict__ w2b)
{
  const int PERE = 2 * F_DIM * (H_DIM / 8);     // chunks per expert (w13)
  for (int c = blockIdx.x * 256 + threadIdx.x; c < TOTC;
       c += gridDim.x * 256) {
    const float* sp;
    char* dp;
    if (c < W13C) {
      int e = c / PERE;
      int r = c - e * PERE;
      int rho = r >> 7;
      int hc = r & 127;
      int f = ((rho >> 5) << 4) + (rho & 15);
      sp = ((rho >> 4) & 1 ? w3 : w1) +
           ((size_t)e * F_DIM + f) * H_DIM + hc * 8;
      dp = (char*)wB + ((size_t)c << 4);        // dst linear in c
    } else {
      int i = c - W13C;
      sp = w2f + (size_t)i * 8;
      dp = (char*)w2b + ((size_t)i << 4);
    }
    const float4* s4 = (const float4*)sp;
    float4 a = s4[0], b = s4[1];
    uintx4 p;
    p.x = pack2bf16(a.x, a.y); p.y = pack2bf16(a.z, a.w);
    p.z = pack2bf16(b.x, b.y); p.w = pack2bf16(b.z, b.w);
    __builtin_nontemporal_store(p, (uintx4*)dp);
  }
}

// ---------------- router ----------------------------------------------------
__global__ __launch_bounds__(256) void router_kernel(
    const float* __restrict__ x, const float* __restrict__ gate,
    float* __restrict__ logits_out, __hip_bfloat16* __restrict__ xb,
    int* __restrict__ counts, int* __restrict__ idx_list,
    float* __restrict__ wgt_list, int* __restrict__ meta0,
    int* __restrict__ meta1, float* __restrict__ wcomb)
{
  const int wv = threadIdx.x >> 6;
  const int lane = threadIdx.x & 63;
  const int t = blockIdx.x * 4 + wv;

  const float4* xr = (const float4*)(x + (size_t)t * H_DIM);
  const float4* g4 = (const float4*)gate;

  float acc[E_NUM];
#pragma unroll
  for (int e = 0; e < E_NUM; ++e) acc[e] = 0.f;

  unsigned* xbo = (unsigned*)(xb + (size_t)t * H_DIM);
#pragma unroll
  for (int j = 0; j < 4; ++j) {
    int i = j * 64 + lane;
    float4 xv = xr[i];
    uint2 pk;
    pk.x = pack2bf16(xv.x, xv.y);
    pk.y = pack2bf16(xv.z, xv.w);
    *(uint2*)(xbo + i * 2) = pk;
#pragma unroll
    for (int e = 0; e < E_NUM; ++e) {
      float4 gv = g4[e * 256 + i];
      acc[e] += xv.x * gv.x + xv.y * gv.y + xv.z * gv.z + xv.w * gv.w;
    }
  }
#pragma unroll
  for (int off = 32; off > 0; off >>= 1) {
#pragma unroll
    for (int e = 0; e < E_NUM; ++e) acc[e] += __shfl_xor(acc[e], off, 64);
  }

  if (lane == 0) {
#pragma unroll
    for (int e = 0; e < E_NUM; ++e) logits_out[(size_t)t * E_NUM + e] = acc[e];
    int i0 = 0; float v0 = acc[0];
#pragma unroll
    for (int e = 1; e < E_NUM; ++e) if (acc[e] > v0) { v0 = acc[e]; i0 = e; }
    int i1 = -1; float v1 = -1e30f;
#pragma unroll
    for (int e = 0; e < E_NUM; ++e)
      if (e != i0 && acc[e] > v1) { v1 = acc[e]; i1 = e; }
    float p1 = __expf(v1 - v0);
    float w0 = 1.f / (1.f + p1);
    float w1 = p1 / (1.f + p1);
    int pos0 = atomicAdd(&counts[i0], 1);
    idx_list[i0 * T_TOK + pos0] = t;
    wgt_list[i0 * T_TOK + pos0] = w0;
    int pos1 = atomicAdd(&counts[i1], 1);
    idx_list[i1 * T_TOK + pos1] = t;
    wgt_list[i1 * T_TOK + pos1] = w1;
    meta0[t] = (i0 << 16) | pos0;
    meta1[t] = (i1 << 16) | pos1;
    wcomb[t] = w0;
  }
}

// ------------- GEMM1: 256x256 tile, 8 waves, BK=64, 2-phase counted vmcnt ---
// R5/R12-proven structure. C = X @ wB^T over interleaved wB;
// silu(even frag)*odd frag in epilogue. Offsets computed inline from counts.
__global__ __launch_bounds__(512, 2) void gemm1_kernel(
    const __hip_bfloat16* __restrict__ xb,
    const __hip_bfloat16* __restrict__ wB,
    const int* __restrict__ counts, const int* __restrict__ idx_list,
    __hip_bfloat16* __restrict__ hidden)
{
  const int e = blockIdx.z;
  const int n_e = counts[e];
  const int tm = blockIdx.y;
  if (n_e == 0 || tm * 256 >= n_e) return;
  const int tn = blockIdx.x;                  // 256 wB rows = 128 f
  const int off_e = prefix_off(counts, e);

  __shared__ char lds[131072];
  char* sA = lds;                             // 2 x 32768
  char* sB = lds + 65536;                     // 2 x 32768

  const int tid = threadIdx.x;
  const int lane = tid & 63;
  const int wv = tid >> 6;                    // 0..7
  const int wrow = (wv >> 2) * 128;           // {0,128}
  const int wcol = (wv & 3) * 64;             // {0,64,128,192}
  const int csw = ((lane & 7) ^ (lane >> 3)) << 4;
  const int wvb = wv * 1024;

  size_t aoff[4];
#pragma unroll
  for (int i = 0; i < 4; ++i) {
    int rr = i * 64 + wv * 8 + (lane >> 3);
    int pos = tm * 256 + rr;
    int p = pos < n_e ? pos : n_e - 1;
    aoff[i] = (size_t)idx_list[e * T_TOK + p] * 2048;
  }
  const char* xbp = (const char*)xb;
  const char* wBp =
      (const char*)wB + ((size_t)e * (2 * F_DIM) + tn * 256) * 2048;
  size_t boff[4];
#pragma unroll
  for (int i = 0; i < 4; ++i)
    boff[i] = (size_t)(i * 64 + wv * 8 + (lane >> 3)) * 2048;

  floatx4 acc[8][4];
#pragma unroll
  for (int m = 0; m < 8; ++m)
#pragma unroll
    for (int n = 0; n < 4; ++n)
#pragma unroll
      for (int q = 0; q < 4; ++q) acc[m][n][q] = 0.f;

#define STAGE1(set, kb)                                                \
  do {                                                                 \
    char* dA = sA + (set) * 32768 + wvb;                               \
    char* dB = sB + (set) * 32768 + wvb;                               \
    _Pragma("unroll")                                                  \
    for (int i = 0; i < 4; ++i) {                                      \
      gload16(xbp + aoff[i] + (kb) + csw, dA + i * 8192);              \
      gload16(wBp + boff[i] + (kb) + csw, dB + i * 8192);              \
    }                                                                  \
  } while (0)

  // drain gather loads so counted vmcnt sees only our DMAs
  asm volatile("s_waitcnt vmcnt(0)" ::: "memory");
  STAGE1(0, 0);

  int cur = 0;
  for (int kt = 0; kt < H_DIM / 64; ++kt) {       // 16 K-tiles
    if (kt < H_DIM / 64 - 1) {
      STAGE1(cur ^ 1, (kt + 1) * 128);
      asm volatile("s_waitcnt vmcnt(8)" ::: "memory");  // this tile landed
    } else {
      asm volatile("s_waitcnt vmcnt(0)" ::: "memory");
    }
    __syncthreads();
    const char* rA = sA + cur * 32768;
    const char* rB = sB + cur * 32768;
#pragma unroll
    for (int kk = 0; kk < 2; ++kk) {
      const int colb = kk * 64 + (lane >> 4) * 16;
      bf16x8 af[8], bx[4];
#pragma unroll
      for (int m = 0; m < 8; ++m)
        af[m] = *(const bf16x8*)(rA + swz(wrow + m * 16 + (lane & 15), colb));
#pragma unroll
      for (int n = 0; n < 4; ++n)
        bx[n] = *(const bf16x8*)(rB + swz(wcol + n * 16 + (lane & 15), colb));
#pragma unroll
      for (int m = 0; m < 8; ++m)
#pragma unroll
        for (int n = 0; n < 4; ++n)
          acc[m][n] = __builtin_amdgcn_mfma_f32_16x16x32_bf16(
              af[m], bx[n], acc[m][n], 0, 0, 0);
    }
    __syncthreads();
    cur ^= 1;
  }
#undef STAGE1

  // epilogue: pair even/odd N-fragments (w1/w3 of same f-block), silu*mul
  const int fbase = (tn * 8 + (wcol >> 5)) * 16 + (lane & 15);
#pragma unroll
  for (int m = 0; m < 8; ++m) {
#pragma unroll
    for (int q = 0; q < 4; ++q) {
      int pos = tm * 256 + wrow + m * 16 + ((lane >> 4) << 2) + q;
      if (pos < n_e) {
        __hip_bfloat16* hrow = hidden + (size_t)(off_e + pos) * F_DIM;
#pragma unroll
        for (int j = 0; j < 2; ++j) {
          float h1 = acc[m][2 * j][q];
          float h3 = acc[m][2 * j + 1][q];
          float h = (h1 / (1.f + __expf(-h1))) * h3;   // silu(h1)*h3
          hrow[fbase + j * 16] = __float2bfloat16(h);
        }
      }
    }
  }
}

// ------------- GEMM2: 128x128 tile, split-K x2, 2-phase counted vmcnt -------
// bz = e + 8*khalf; bf16 partials in y[khalf] (slot space 2*T_TOK rows each).
__global__ __launch_bounds__(256, 2) void gemm2_kernel(
    const __hip_bfloat16* __restrict__ hidden,
    const __hip_bfloat16* __restrict__ w2b,
    const int* __restrict__ counts, __hip_bfloat16* __restrict__ y)
{
  const int e = blockIdx.z & 7;
  const int kh = blockIdx.z >> 3;             // K-half 0/1
  const int tm = blockIdx.y;                  // 0..31
  const int tn = blockIdx.x;                  // 0..7
  const int n_e = counts[e];
  if (n_e == 0 || tm * 128 >= n_e) return;
  const int n0 = tn * 128;
  const int off_e = prefix_off(counts, e);
  const int kbase = kh * (F_DIM);             // byte base = kh*22*128

  __shared__ char lds[65536];
  char* sA = lds;                             // 2 x 16384
  char* sB = lds + 32768;                     // 2 x 16384

  const int tid = threadIdx.x;
  const int lane = tid & 63;
  const int wv = tid >> 6;
  const int wrow = (wv >> 1) * 64;
  const int wcol = (wv & 1) * 64;
  const int csw = ((lane & 7) ^ (lane >> 3)) << 4;
  const int wvb = wv * 1024;

  size_t aoff[4], boff[4];
#pragma unroll
  for (int i = 0; i < 4; ++i) {
    int rr = i * 32 + wv * 8 + (lane >> 3);
    int pos = tm * 128 + rr;
    int p = pos < n_e ? pos : n_e - 1;
    aoff[i] = (size_t)(off_e + p) * (F_DIM * 2);
    boff[i] = ((size_t)e * H_DIM + n0 + rr) * (F_DIM * 2);
  }
  const char* hp = (const char*)hidden;
  const char* w2p = (const char*)w2b;

  floatx4 acc[4][4];
#pragma unroll
  for (int m = 0; m < 4; ++m)
#pragma unroll
    for (int n = 0; n < 4; ++n)
#pragma unroll
      for (int q = 0; q < 4; ++q) acc[m][n][q] = 0.f;

#define STAGE2(set, kb)                                                \
  do {                                                                 \
    char* dA = sA + (set) * 16384 + wvb;                               \
    char* dB = sB + (set) * 16384 + wvb;                               \
    _Pragma("unroll")                                                  \
    for (int i = 0; i < 4; ++i) {                                      \
      gload16(hp + aoff[i] + (kb) + csw, dA + i * 4096);               \
      gload16(w2p + boff[i] + (kb) + csw, dB + i * 4096);              \
    }                                                                  \
  } while (0)

  asm volatile("s_waitcnt vmcnt(0)" ::: "memory");
  STAGE2(0, kbase);

  int cur = 0;
  const int NKT = F_DIM / 64 / 2;             // 22 K-tiles per half
  for (int kt = 0; kt < NKT; ++kt) {
    if (kt < NKT - 1) {
      STAGE2(cur ^ 1, kbase + (kt + 1) * 128);
      asm volatile("s_waitcnt vmcnt(8)" ::: "memory");
    } else {
      asm volatile("s_waitcnt vmcnt(0)" ::: "memory");
    }
    __syncthreads();
    const char* rA = sA + cur * 16384;
    const char* rB = sB + cur * 16384;
#pragma unroll
    for (int kk = 0; kk < 2; ++kk) {
      const int colb = kk * 64 + (lane >> 4) * 16;
      bf16x8 af[4], bx[4];
#pragma unroll
      for (int m = 0; m < 4; ++m)
        af[m] = *(const bf16x8*)(rA + swz(wrow + m * 16 + (lane & 15), colb));
#pragma unroll
      for (int n = 0; n < 4; ++n)
        bx[n] = *(const bf16x8*)(rB + swz(wcol + n * 16 + (lane & 15), colb));
#pragma unroll
      for (int m = 0; m < 4; ++m)
#pragma unroll
        for (int n = 0; n < 4; ++n)
          acc[m][n] = __builtin_amdgcn_mfma_f32_16x16x32_bf16(
              af[m], bx[n], acc[m][n], 0, 0, 0);
    }
    __syncthreads();
    cur ^= 1;
  }
#undef STAGE2

  // slot space per half = 2*T_TOK rows (8192 token-expert slots)
  __hip_bfloat16* yh = y + (size_t)kh * (2 * T_TOK) * H_DIM;
#pragma unroll
  for (int m = 0; m < 4; ++m) {
#pragma unroll
    for (int q = 0; q < 4; ++q) {
      int pos = tm * 128 + wrow + m * 16 + ((lane >> 4) << 2) + q;
      if (pos < n_e) {
        __hip_bfloat16* yrow = yh + (size_t)(off_e + pos) * H_DIM + n0;
#pragma unroll
        for (int n = 0; n < 4; ++n)
          yrow[wcol + n * 16 + (lane & 15)] = __float2bfloat16(acc[m][n][q]);
      }
    }
  }
}

// ------------- combine: out[t] = w0*(y0+y1)[slot0] + (1-w0)*(y0+y1)[slot1] --
__global__ __launch_bounds__(256) void combine_kernel(
    const __hip_bfloat16* __restrict__ y, const int* __restrict__ counts,
    const int* __restrict__ meta0, const int* __restrict__ meta1,
    const float* __restrict__ wcomb, float* __restrict__ out)
{
  const int t = blockIdx.x;
  const int m0 = meta0[t], m1 = meta1[t];
  const int i0 = m0 >> 16, i1 = m1 >> 16;
  int o0 = 0, o1 = 0;
#pragma unroll
  for (int i = 0; i < E_NUM; ++i) {
    int c = counts[i];
    o0 += (i < i0) ? c : 0;
    o1 += (i < i1) ? c : 0;
  }
  const float w0 = wcomb[t];
  const float w1 = 1.f - w0;
  const size_t s0 = (size_t)(o0 + (m0 & 0xffff)) * H_DIM;
  const size_t s1 = (size_t)(o1 + (m1 & 0xffff)) * H_DIM;
  const size_t HB = (size_t)(2 * T_TOK) * H_DIM;  // second K-half offset
  const int c = threadIdx.x * 4;
  ushort4 a0 = *(const ushort4*)(y + s0 + c);
  ushort4 a1 = *(const ushort4*)(y + HB + s0 + c);
  ushort4 b0 = *(const ushort4*)(y + s1 + c);
  ushort4 b1 = *(const ushort4*)(y + HB + s1 + c);
  float4 o;
  o.x = w0 * (b2f(a0.x) + b2f(a1.x)) + w1 * (b2f(b0.x) + b2f(b1.x));
  o.y = w0 * (b2f(a0.y) + b2f(a1.y)) + w1 * (b2f(b0.y) + b2f(b1.y));
  o.z = w0 * (b2f(a0.z) + b2f(a1.z)) + w1 * (b2f(b0.z) + b2f(b1.z));
  o.w = w0 * (b2f(a0.w) + b2f(a1.w)) + w1 * (b2f(b0.w) + b2f(b1.w));
  *(float4*)(out + (size_t)t * H_DIM + c) = o;
}

// =================== fallback path (round-1-proven kernels) ================
__global__ __launch_bounds__(256) void router_fb(
    const float* __restrict__ x, const float* __restrict__ gate,
    float* __restrict__ logits_out, __hip_bfloat16* __restrict__ xb,
    int* __restrict__ counts, int* __restrict__ idx_list,
    float* __restrict__ wgt_list)
{
  const int wv = threadIdx.x >> 6;
  const int lane = threadIdx.x & 63;
  const int t = blockIdx.x * 4 + wv;
  const float4* xr = (const float4*)(x + (size_t)t * H_DIM);
  const float4* g4 = (const float4*)gate;
  float acc[E_NUM];
#pragma unroll
  for (int e = 0; e < E_NUM; ++e) acc[e] = 0.f;
  unsigned* xbo = (unsigned*)(xb + (size_t)t * H_DIM);
#pragma unroll
  for (int j = 0; j < 4; ++j) {
    int i = j * 64 + lane;
    float4 xv = xr[i];
    uint2 pk;
    pk.x = pack2bf16(xv.x, xv.y);
    pk.y = pack2bf16(xv.z, xv.w);
    *(uint2*)(xbo + i * 2) = pk;
#pragma unroll
    for (int e = 0; e < E_NUM; ++e) {
      float4 gv = g4[e * 256 + i];
      acc[e] += xv.x * gv.x + xv.y * gv.y + xv.z * gv.z + xv.w * gv.w;
    }
  }
#pragma unroll
  for (int off = 32; off > 0; off >>= 1) {
#pragma unroll
    for (int e = 0; e < E_NUM; ++e) acc[e] += __shfl_xor(acc[e], off, 64);
  }
  if (lane == 0) {
#pragma unroll
    for (int e = 0; e < E_NUM; ++e) logits_out[(size_t)t * E_NUM + e] = acc[e];
    int i0 = 0; float v0 = acc[0];
#pragma unroll
    for (int e = 1; e < E_NUM; ++e) if (acc[e] > v0) { v0 = acc[e]; i0 = e; }
    int i1 = -1; float v1 = -1e30f;
#pragma unroll
    for (int e = 0; e < E_NUM; ++e)
      if (e != i0 && acc[e] > v1) { v1 = acc[e]; i1 = e; }
    float p1 = __expf(v1 - v0);
    float w0 = 1.f / (1.f + p1);
    float w1 = p1 / (1.f + p1);
    int pos0 = atomicAdd(&counts[i0], 1);
    idx_list[i0 * T_TOK + pos0] = t;
    wgt_list[i0 * T_TOK + pos0] = w0;
    int pos1 = atomicAdd(&counts[i1], 1);
    idx_list[i1 * T_TOK + pos1] = t;
    wgt_list[i1 * T_TOK + pos1] = w1;
  }
}

__global__ __launch_bounds__(256) void gemm1_fb(
    const __hip_bfloat16* __restrict__ xb,
    const float* __restrict__ w1, const float* __restrict__ w3,
    const int* __restrict__ counts, const int* __restrict__ idx_list,
    __hip_bfloat16* __restrict__ hidden)
{
  const int e = blockIdx.z;
  const int n_e = counts[e];
  const int tm = blockIdx.y;
  if (n_e == 0 || tm * 128 >= n_e) return;
  const int tn = blockIdx.x;
  const int f0 = tn * 128;
  const int off_e = prefix_off(counts, e);

  __shared__ short sA[128 * 64];
  __shared__ short sB1[128 * 64];
  __shared__ short sB3[128 * 64];
  __shared__ int s_row[128];

  const int tid = threadIdx.x;
  if (tid < 128) {
    int pos = tm * 128 + tid;
    int p = pos < n_e ? pos : n_e - 1;
    s_row[tid] = idx_list[e * T_TOK + p];
  }
  const int lane = tid & 63;
  const int wv = tid >> 6;
  const int wrow = (wv >> 1) * 64;
  const int wcol = (wv & 1) * 64;
  const int cc = tid & 7;
  const int rbase = tid >> 3;

  floatx4 acc1[4][4], acc3[4][4];
#pragma unroll
  for (int m = 0; m < 4; ++m)
#pragma unroll
    for (int n = 0; n < 4; ++n)
#pragma unroll
      for (int q = 0; q < 4; ++q) { acc1[m][n][q] = 0.f; acc3[m][n][q] = 0.f; }

  const float* w1e = w1 + (size_t)e * F_DIM * H_DIM + (size_t)f0 * H_DIM;
  const float* w3e = w3 + (size_t)e * F_DIM * H_DIM + (size_t)f0 * H_DIM;

  for (int kt = 0; kt < H_DIM / 64; ++kt) {
    const int k0 = kt * 64;
    __syncthreads();
#pragma unroll
    for (int i = 0; i < 4; ++i) {
      int rr = rbase + 32 * i;
      uint4 av = *(const uint4*)(xb + (size_t)s_row[rr] * H_DIM + k0 + cc * 8);
      *(uint4*)((char*)sA + swz(rr, cc * 16)) = av;
      const float4* p1 = (const float4*)(w1e + (size_t)rr * H_DIM + k0 + cc * 8);
      float4 a1 = p1[0], b1 = p1[1];
      uint4 pb1;
      pb1.x = pack2bf16(a1.x, a1.y); pb1.y = pack2bf16(a1.z, a1.w);
      pb1.z = pack2bf16(b1.x, b1.y); pb1.w = pack2bf16(b1.z, b1.w);
      *(uint4*)((char*)sB1 + swz(rr, cc * 16)) = pb1;
      const float4* p3 = (const float4*)(w3e + (size_t)rr * H_DIM + k0 + cc * 8);
      float4 a3 = p3[0], b3 = p3[1];
      uint4 pb3;
      pb3.x = pack2bf16(a3.x, a3.y); pb3.y = pack2bf16(a3.z, a3.w);
      pb3.z = pack2bf16(b3.x, b3.y); pb3.w = pack2bf16(b3.z, b3.w);
      *(uint4*)((char*)sB3 + swz(rr, cc * 16)) = pb3;
    }
    __syncthreads();
#pragma unroll
    for (int kk = 0; kk < 2; ++kk) {
      const int colb = kk * 64 + (lane >> 4) * 16;
      bf16x8 af[4], bf1[4], bf3[4];
#pragma unroll
      for (int m = 0; m < 4; ++m)
        af[m] = *(const bf16x8*)((const char*)sA +
                                 swz(wrow + m * 16 + (lane & 15), colb));
#pragma unroll
      for (int n = 0; n < 4; ++n) {
        bf1[n] = *(const bf16x8*)((const char*)sB1 +
                                  swz(wcol + n * 16 + (lane & 15), colb));
        bf3[n] = *(const bf16x8*)((const char*)sB3 +
                                  swz(wcol + n * 16 + (lane & 15), colb));
      }
#pragma unroll
      for (int m = 0; m < 4; ++m)
#pragma unroll
        for (int n = 0; n < 4; ++n) {
          acc1[m][n] = __builtin_amdgcn_mfma_f32_16x16x32_bf16(
              af[m], bf1[n], acc1[m][n], 0, 0, 0);
          acc3[m][n] = __builtin_amdgcn_mfma_f32_16x16x32_bf16(
              af[m], bf3[n], acc3[m][n], 0, 0, 0);
        }
    }
  }
#pragma unroll
  for (int m = 0; m < 4; ++m) {
#pragma unroll
    for (int q = 0; q < 4; ++q) {
      int rl = wrow + m * 16 + ((lane >> 4) << 2) + q;
      int pos = tm * 128 + rl;
      if (pos < n_e) {
        __hip_bfloat16* hrow = hidden + (size_t)(off_e + pos) * F_DIM + f0;
#pragma unroll
        for (int n = 0; n < 4; ++n) {
          float h1 = acc1[m][n][q];
          float h3 = acc3[m][n][q];
          float h = (h1 / (1.f + __expf(-h1))) * h3;
          hrow[wcol + n * 16 + (lane & 15)] = __float2bfloat16(h);
        }
      }
    }
  }
}

__global__ __launch_bounds__(256) void gemm2_fb(
    const __hip_bfloat16* __restrict__ hidden, const float* __restrict__ w2,
    const int* __restrict__ counts, const int* __restrict__ idx_list,
    const float* __restrict__ wgt_list, float* __restrict__ out)
{
  const int e = blockIdx.z;
  const int n_e = counts[e];
  const int tm = blockIdx.y;
  if (n_e == 0 || tm * 128 >= n_e) return;
  const int tn = blockIdx.x;
  const int n0 = tn * 128;
  const int off_e = prefix_off(counts, e);

  __shared__ short sA[128 * 64];
  __shared__ short sB[128 * 64];
  __shared__ int s_tok[128];
  __shared__ float s_wgt[128];

  const int tid = threadIdx.x;
  if (tid < 128) {
    int pos = tm * 128 + tid;
    if (pos < n_e) {
      s_tok[tid] = idx_list[e * T_TOK + pos];
      s_wgt[tid] = wgt_list[e * T_TOK + pos];
    } else {
      s_tok[tid] = -1;
      s_wgt[tid] = 0.f;
    }
  }
  const int lane = tid & 63;
  const int wv = tid >> 6;
  const int wrow = (wv >> 1) * 64;
  const int wcol = (wv & 1) * 64;
  const int cc = tid & 7;
  const int rbase = tid >> 3;

  floatx4 acc[4][4];
#pragma unroll
  for (int m = 0; m < 4; ++m)
#pragma unroll
    for (int n = 0; n < 4; ++n)
#pragma unroll
      for (int q = 0; q < 4; ++q) acc[m][n][q] = 0.f;

  const float* w2e = w2 + (size_t)e * H_DIM * F_DIM + (size_t)n0 * F_DIM;

  for (int kt = 0; kt < F_DIM / 64; ++kt) {
    const int k0 = kt * 64;
    __syncthreads();
#pragma unroll
    for (int i = 0; i < 4; ++i) {
      int rr = rbase + 32 * i;
      int pos = tm * 128 + rr;
      int pr = pos < n_e ? pos : n_e - 1;
      uint4 av = *(const uint4*)(hidden + (size_t)(off_e + pr) * F_DIM +
                                 k0 + cc * 8);
      *(uint4*)((char*)sA + swz(rr, cc * 16)) = av;
      const float4* pb = (const float4*)(w2e + (size_t)rr * F_DIM + k0 + cc * 8);
      float4 ba = pb[0], bb = pb[1];
      uint4 pk;
      pk.x = pack2bf16(ba.x, ba.y); pk.y = pack2bf16(ba.z, ba.w);
      pk.z = pack2bf16(bb.x, bb.y); pk.w = pack2bf16(bb.z, bb.w);
      *(uint4*)((char*)sB + swz(rr, cc * 16)) = pk;
    }
    __syncthreads();
#pragma unroll
    for (int kk = 0; kk < 2; ++kk) {
      const int colb = kk * 64 + (lane >> 4) * 16;
      bf16x8 af[4], bf[4];
#pragma unroll
      for (int m = 0; m < 4; ++m)
        af[m] = *(const bf16x8*)((const char*)sA +
                                 swz(wrow + m * 16 + (lane & 15), colb));
#pragma unroll
      for (int n = 0; n < 4; ++n)
        bf[n] = *(const bf16x8*)((const char*)sB +
                                 swz(wcol + n * 16 + (lane & 15), colb));
#pragma unroll
      for (int m = 0; m < 4; ++m)
#pragma unroll
        for (int n = 0; n < 4; ++n)
          acc[m][n] = __builtin_amdgcn_mfma_f32_16x16x32_bf16(
              af[m], bf[n], acc[m][n], 0, 0, 0);
    }
  }
#pragma unroll
  for (int m = 0; m < 4; ++m) {
#pragma unroll
    for (int q = 0; q < 4; ++q) {
      int rl = wrow + m * 16 + ((lane >> 4) << 2) + q;
      int tok = s_tok[rl];
      if (tok >= 0) {
        float wgt = s_wgt[rl];
        float* orow = out + (size_t)tok * H_DIM + n0;
#pragma unroll
        for (int n = 0; n < 4; ++n)
          atomicAdd(&orow[wcol + n * 16 + (lane & 15)], wgt * acc[m][n][q]);
      }
    }
  }
}

extern "C" void kernel_launch(void* const* d_in, const int* in_sizes, int n_in,
                              void* d_out, int out_size, void* d_ws,
                              size_t ws_size, hipStream_t stream) {
  const float* x = (const float*)d_in[0];
  const float* gate = (const float*)d_in[1];
  const float* w1 = (const float*)d_in[2];
  const float* w3 = (const float*)d_in[3];
  const float* w2 = (const float*)d_in[4];

  float* out = (float*)d_out;                        // [T, H]
  float* logits = out + (size_t)T_TOK * H_DIM;       // [T, E]

  char* ws = (char*)d_ws;
  const size_t o_idx = 256;
  const size_t o_wgt = o_idx + (size_t)E_NUM * T_TOK * 4;
  const size_t o_m0  = o_wgt + (size_t)E_NUM * T_TOK * 4;
  const size_t o_m1  = o_m0 + (size_t)T_TOK * 4;
  const size_t o_wc  = o_m1 + (size_t)T_TOK * 4;
  const size_t o_xb  = o_wc + (size_t)T_TOK * 4;
  const size_t o_hid = o_xb + (size_t)T_TOK * H_DIM * 2;
  const size_t o_wB  = o_hid + (size_t)2 * T_TOK * F_DIM * 2;
  const size_t o_w2b = o_wB + (size_t)E_NUM * 2 * F_DIM * H_DIM * 2;
  const size_t need  = o_w2b + (size_t)E_NUM * H_DIM * F_DIM * 2;  // ~184 MiB

  int* counts = (int*)ws;
  int* idx_list = (int*)(ws + o_idx);
  float* wgt_list = (float*)(ws + o_wgt);
  int* meta0 = (int*)(ws + o_m0);
  int* meta1 = (int*)(ws + o_m1);
  float* wcomb = (float*)(ws + o_wc);
  __hip_bfloat16* xb = (__hip_bfloat16*)(ws + o_xb);
  __hip_bfloat16* hidden = (__hip_bfloat16*)(ws + o_hid);

  hipMemsetAsync(counts, 0, 64, stream);

  if (ws_size >= need) {
    __hip_bfloat16* wB = (__hip_bfloat16*)(ws + o_wB);
    __hip_bfloat16* w2b = (__hip_bfloat16*)(ws + o_w2b);
    __hip_bfloat16* y = (__hip_bfloat16*)(ws + o_wB);   // alias: wB dead then
                                                        // (2 halves = 34 MB)

    convert_all<<<4096, 256, 0, stream>>>(w1, w3, w2, wB, w2b);
    router_kernel<<<T_TOK / 4, 256, 0, stream>>>(
        x, gate, logits, xb, counts, idx_list, wgt_list, meta0, meta1, wcomb);
    gemm1_kernel<<<dim3(2 * F_DIM / 256, T_TOK / 256, E_NUM), 512, 0,
                   stream>>>(xb, wB, counts, idx_list, hidden);
    gemm2_kernel<<<dim3(8, 32, 2 * E_NUM), 256, 0, stream>>>(
        hidden, w2b, counts, y);
    combine_kernel<<<T_TOK, 256, 0, stream>>>(y, counts, meta0, meta1, wcomb,
                                              out);
  } else {
    hipMemsetAsync(out, 0, (size_t)T_TOK * H_DIM * sizeof(float), stream);
    router_fb<<<T_TOK / 4, 256, 0, stream>>>(x, gate, logits, xb, counts,
                                             idx_list, wgt_list);
    gemm1_fb<<<dim3(F_DIM / 128, T_TOK / 128, E_NUM), 256, 0, stream>>>(
        xb, w1, w3, counts, idx_list, hidden);
    gemm2_fb<<<dim3(H_DIM / 128, T_TOK / 128, E_NUM), 256, 0, stream>>>(
        hidden, w2, counts, idx_list, wgt_list, out);
  }
}

// Round 16
// 445.911 us; speedup vs baseline: 1.0181x; 1.0181x over previous
//
#include <hip/hip_runtime.h>
#include <hip/hip_bf16.h>
#include <stdint.h>

#define T_TOK 4096
#define H_DIM 1024
#define F_DIM 2816
#define E_NUM 8

typedef __attribute__((ext_vector_type(8))) __bf16 bf16x8;
typedef __attribute__((ext_vector_type(4))) float floatx4;
typedef __attribute__((ext_vector_type(4))) unsigned int uintx4;
typedef __attribute__((address_space(3))) char lds_char;
typedef __attribute__((address_space(1))) const char glb_char;

// async 16B global->LDS (dest = wave-uniform base + lane*16)
__device__ __forceinline__ void gload16(const void* g, void* l) {
  __builtin_amdgcn_global_load_lds((glb_char*)g, (lds_char*)l, 16, 0, 0);
}

// round-to-nearest-even fp32 -> bf16, packed 2-at-a-time
__device__ __forceinline__ unsigned pack2bf16(float a, float b) {
  unsigned ua = __builtin_bit_cast(unsigned, a);
  unsigned ub = __builtin_bit_cast(unsigned, b);
  ua += 0x7fffu + ((ua >> 16) & 1u);
  ub += 0x7fffu + ((ub >> 16) & 1u);
  return (ua >> 16) | (ub & 0xffff0000u);
}

__device__ __forceinline__ float b2f(unsigned short u) {
  unsigned v = ((unsigned)u) << 16;
  return __builtin_bit_cast(float, v);
}

// XOR swizzle for [row][64 bf16] LDS tiles (128 B rows): proven 0-conflict.
__device__ __forceinline__ int swz(int row, int colb) {
  return (row * 128 + colb) ^ ((row & 7) << 4);
}

// inline exclusive-prefix of counts[0..7] below expert e (branchless, no array)
__device__ __forceinline__ int prefix_off(const int* __restrict__ counts,
                                          int e) {
  int o = 0;
#pragma unroll
  for (int i = 0; i < E_NUM; ++i) o += (i < e) ? counts[i] : 0;
  return o;
}

// ---------------- merged prep: w13 convert | w2 convert | router ------------
// blocks [0, 22528): w13 interleaved convert -> wB[e][rho][h]
//   rho in 32-row groups of [16 w1-rows | 16 w3-rows]; f=(rho>>5)*16+(rho&15)
// blocks [22528, 33792): w2 fp32->bf16 convert (exact cover)
// blocks [33792, 34816): router (4 tokens per block)
// bf16 writes are nontemporal: write-once data, keep L2/L3 for fp32 reads.
#define NB_W13 (F_DIM * E_NUM)
#define NB_W2  (E_NUM * F_DIM * H_DIM / 8 / 256)
#define NB_RT  (T_TOK / 4)
__global__ __launch_bounds__(256) void prep_kernel(
    const float* __restrict__ w1, const float* __restrict__ w3,
    const float* __restrict__ w2f, const float* __restrict__ x,
    const float* __restrict__ gate, __hip_bfloat16* __restrict__ wB,
    __hip_bfloat16* __restrict__ w2b, float* __restrict__ logits_out,
    __hip_bfloat16* __restrict__ xb, int* __restrict__ counts,
    int* __restrict__ idx_list, float* __restrict__ wgt_list,
    int* __restrict__ meta0, int* __restrict__ meta1,
    float* __restrict__ wcomb)
{
  const int bid = blockIdx.x;
  if (bid < NB_W13) {
    const int e = bid / F_DIM;
    const int bx = bid - e * F_DIM;
    const int rho = bx * 2 + (threadIdx.x >> 7);
    const int hc = threadIdx.x & 127;               // 8-float chunk in row
    const int f = ((rho >> 5) << 4) + (rho & 15);
    const float* src = ((rho >> 4) & 1 ? w3 : w1) +
                       ((size_t)e * F_DIM + f) * H_DIM + hc * 8;
    const float4* s = (const float4*)src;
    float4 a = s[0], b = s[1];
    uintx4 p;
    p.x = pack2bf16(a.x, a.y); p.y = pack2bf16(a.z, a.w);
    p.z = pack2bf16(b.x, b.y); p.w = pack2bf16(b.z, b.w);
    __builtin_nontemporal_store(
        p, (uintx4*)((char*)wB +
                     (((size_t)e * (2 * F_DIM) + rho) * H_DIM + hc * 8) * 2));
    return;
  }
  if (bid < NB_W13 + NB_W2) {
    const size_t i = (size_t)(bid - NB_W13) * 256 + threadIdx.x;  // chunk8
    const float4* s = (const float4*)(w2f + i * 8);
    float4 a = s[0], b = s[1];
    uintx4 p;
    p.x = pack2bf16(a.x, a.y); p.y = pack2bf16(a.z, a.w);
    p.z = pack2bf16(b.x, b.y); p.w = pack2bf16(b.z, b.w);
    __builtin_nontemporal_store(p, (uintx4*)((char*)w2b + i * 16));
    return;
  }
  // ------- router section -------
  const int blk = bid - (NB_W13 + NB_W2);
  const int wv = threadIdx.x >> 6;
  const int lane = threadIdx.x & 63;
  const int t = blk * 4 + wv;

  const float4* xr = (const float4*)(x + (size_t)t * H_DIM);
  const float4* g4 = (const float4*)gate;

  float acc[E_NUM];
#pragma unroll
  for (int e = 0; e < E_NUM; ++e) acc[e] = 0.f;

  unsigned* xbo = (unsigned*)(xb + (size_t)t * H_DIM);
#pragma unroll
  for (int j = 0; j < 4; ++j) {
    int i = j * 64 + lane;
    float4 xv = xr[i];
    uint2 pk;
    pk.x = pack2bf16(xv.x, xv.y);
    pk.y = pack2bf16(xv.z, xv.w);
    *(uint2*)(xbo + i * 2) = pk;
#pragma unroll
    for (int e = 0; e < E_NUM; ++e) {
      float4 gv = g4[e * 256 + i];
      acc[e] += xv.x * gv.x + xv.y * gv.y + xv.z * gv.z + xv.w * gv.w;
    }
  }
#pragma unroll
  for (int off = 32; off > 0; off >>= 1) {
#pragma unroll
    for (int e = 0; e < E_NUM; ++e) acc[e] += __shfl_xor(acc[e], off, 64);
  }

  if (lane == 0) {
#pragma unroll
    for (int e = 0; e < E_NUM; ++e) logits_out[(size_t)t * E_NUM + e] = acc[e];
    int i0 = 0; float v0 = acc[0];
#pragma unroll
    for (int e = 1; e < E_NUM; ++e) if (acc[e] > v0) { v0 = acc[e]; i0 = e; }
    int i1 = -1; float v1 = -1e30f;
#pragma unroll
    for (int e = 0; e < E_NUM; ++e)
      if (e != i0 && acc[e] > v1) { v1 = acc[e]; i1 = e; }
    float p1 = __expf(v1 - v0);
    float w0 = 1.f / (1.f + p1);
    float w1 = p1 / (1.f + p1);
    int pos0 = atomicAdd(&counts[i0], 1);
    idx_list[i0 * T_TOK + pos0] = t;
    wgt_list[i0 * T_TOK + pos0] = w0;
    int pos1 = atomicAdd(&counts[i1], 1);
    idx_list[i1 * T_TOK + pos1] = t;
    wgt_list[i1 * T_TOK + pos1] = w1;
    meta0[t] = (i0 << 16) | pos0;
    meta1[t] = (i1 << 16) | pos1;
    wcomb[t] = w0;
  }
}

// ------------- GEMM1: 256x256 tile, 8 waves, BK=64, 2-phase counted vmcnt ---
// R5/R12-proven structure. C = X @ wB^T over interleaved wB;
// silu(even frag)*odd frag in epilogue. Offsets computed inline from counts.
__global__ __launch_bounds__(512, 2) void gemm1_kernel(
    const __hip_bfloat16* __restrict__ xb,
    const __hip_bfloat16* __restrict__ wB,
    const int* __restrict__ counts, const int* __restrict__ idx_list,
    __hip_bfloat16* __restrict__ hidden)
{
  const int e = blockIdx.z;
  const int n_e = counts[e];
  const int tm = blockIdx.y;
  if (n_e == 0 || tm * 256 >= n_e) return;
  const int tn = blockIdx.x;                  // 256 wB rows = 128 f
  const int off_e = prefix_off(counts, e);

  __shared__ char lds[131072];
  char* sA = lds;                             // 2 x 32768
  char* sB = lds + 65536;                     // 2 x 32768

  const int tid = threadIdx.x;
  const int lane = tid & 63;
  const int wv = tid >> 6;                    // 0..7
  const int wrow = (wv >> 2) * 128;           // {0,128}
  const int wcol = (wv & 3) * 64;             // {0,64,128,192}
  const int csw = ((lane & 7) ^ (lane >> 3)) << 4;
  const int wvb = wv * 1024;

  size_t aoff[4];
#pragma unroll
  for (int i = 0; i < 4; ++i) {
    int rr = i * 64 + wv * 8 + (lane >> 3);
    int pos = tm * 256 + rr;
    int p = pos < n_e ? pos : n_e - 1;
    aoff[i] = (size_t)idx_list[e * T_TOK + p] * 2048;
  }
  const char* xbp = (const char*)xb;
  const char* wBp =
      (const char*)wB + ((size_t)e * (2 * F_DIM) + tn * 256) * 2048;
  size_t boff[4];
#pragma unroll
  for (int i = 0; i < 4; ++i)
    boff[i] = (size_t)(i * 64 + wv * 8 + (lane >> 3)) * 2048;

  floatx4 acc[8][4];
#pragma unroll
  for (int m = 0; m < 8; ++m)
#pragma unroll
    for (int n = 0; n < 4; ++n)
#pragma unroll
      for (int q = 0; q < 4; ++q) acc[m][n][q] = 0.f;

#define STAGE1(set, kb)                                                \
  do {                                                                 \
    char* dA = sA + (set) * 32768 + wvb;                               \
    char* dB = sB + (set) * 32768 + wvb;                               \
    _Pragma("unroll")                                                  \
    for (int i = 0; i < 4; ++i) {                                      \
      gload16(xbp + aoff[i] + (kb) + csw, dA + i * 8192);              \
      gload16(wBp + boff[i] + (kb) + csw, dB + i * 8192);              \
    }                                                                  \
  } while (0)

  // drain gather loads so counted vmcnt sees only our DMAs
  asm volatile("s_waitcnt vmcnt(0)" ::: "memory");
  STAGE1(0, 0);

  int cur = 0;
  for (int kt = 0; kt < H_DIM / 64; ++kt) {       // 16 K-tiles
    if (kt < H_DIM / 64 - 1) {
      STAGE1(cur ^ 1, (kt + 1) * 128);
      asm volatile("s_waitcnt vmcnt(8)" ::: "memory");  // this tile landed
    } else {
      asm volatile("s_waitcnt vmcnt(0)" ::: "memory");
    }
    __syncthreads();
    const char* rA = sA + cur * 32768;
    const char* rB = sB + cur * 32768;
#pragma unroll
    for (int kk = 0; kk < 2; ++kk) {
      const int colb = kk * 64 + (lane >> 4) * 16;
      bf16x8 af[8], bx[4];
#pragma unroll
      for (int m = 0; m < 8; ++m)
        af[m] = *(const bf16x8*)(rA + swz(wrow + m * 16 + (lane & 15), colb));
#pragma unroll
      for (int n = 0; n < 4; ++n)
        bx[n] = *(const bf16x8*)(rB + swz(wcol + n * 16 + (lane & 15), colb));
#pragma unroll
      for (int m = 0; m < 8; ++m)
#pragma unroll
        for (int n = 0; n < 4; ++n)
          acc[m][n] = __builtin_amdgcn_mfma_f32_16x16x32_bf16(
              af[m], bx[n], acc[m][n], 0, 0, 0);
    }
    __syncthreads();
    cur ^= 1;
  }
#undef STAGE1

  // epilogue: pair even/odd N-fragments (w1/w3 of same f-block), silu*mul
  const int fbase = (tn * 8 + (wcol >> 5)) * 16 + (lane & 15);
#pragma unroll
  for (int m = 0; m < 8; ++m) {
#pragma unroll
    for (int q = 0; q < 4; ++q) {
      int pos = tm * 256 + wrow + m * 16 + ((lane >> 4) << 2) + q;
      if (pos < n_e) {
        __hip_bfloat16* hrow = hidden + (size_t)(off_e + pos) * F_DIM;
#pragma unroll
        for (int j = 0; j < 2; ++j) {
          float h1 = acc[m][2 * j][q];
          float h3 = acc[m][2 * j + 1][q];
          float h = (h1 / (1.f + __expf(-h1))) * h3;   // silu(h1)*h3
          hrow[fbase + j * 16] = __float2bfloat16(h);
        }
      }
    }
  }
}

// ------------- GEMM2: 128x128 tile, split-K x2, 2-phase counted vmcnt -------
// bz = e + 8*khalf; bf16 partials in y[khalf] (slot space 2*T_TOK rows each).
__global__ __launch_bounds__(256, 2) void gemm2_kernel(
    const __hip_bfloat16* __restrict__ hidden,
    const __hip_bfloat16* __restrict__ w2b,
    const int* __restrict__ counts, __hip_bfloat16* __restrict__ y)
{
  const int e = blockIdx.z & 7;
  const int kh = blockIdx.z >> 3;             // K-half 0/1
  const int tm = blockIdx.y;                  // 0..31
  const int tn = blockIdx.x;                  // 0..7
  const int n_e = counts[e];
  if (n_e == 0 || tm * 128 >= n_e) return;
  const int n0 = tn * 128;
  const int off_e = prefix_off(counts, e);
  const int kbase = kh * (F_DIM);             // byte base = kh*22*128

  __shared__ char lds[65536];
  char* sA = lds;                             // 2 x 16384
  char* sB = lds + 32768;                     // 2 x 16384

  const int tid = threadIdx.x;
  const int lane = tid & 63;
  const int wv = tid >> 6;
  const int wrow = (wv >> 1) * 64;
  const int wcol = (wv & 1) * 64;
  const int csw = ((lane & 7) ^ (lane >> 3)) << 4;
  const int wvb = wv * 1024;

  size_t aoff[4], boff[4];
#pragma unroll
  for (int i = 0; i < 4; ++i) {
    int rr = i * 32 + wv * 8 + (lane >> 3);
    int pos = tm * 128 + rr;
    int p = pos < n_e ? pos : n_e - 1;
    aoff[i] = (size_t)(off_e + p) * (F_DIM * 2);
    boff[i] = ((size_t)e * H_DIM + n0 + rr) * (F_DIM * 2);
  }
  const char* hp = (const char*)hidden;
  const char* w2p = (const char*)w2b;

  floatx4 acc[4][4];
#pragma unroll
  for (int m = 0; m < 4; ++m)
#pragma unroll
    for (int n = 0; n < 4; ++n)
#pragma unroll
      for (int q = 0; q < 4; ++q) acc[m][n][q] = 0.f;

#define STAGE2(set, kb)                                                \
  do {                                                                 \
    char* dA = sA + (set) * 16384 + wvb;                               \
    char* dB = sB + (set) * 16384 + wvb;                               \
    _Pragma("unroll")                                                  \
    for (int i = 0; i < 4; ++i) {                                      \
      gload16(hp + aoff[i] + (kb) + csw, dA + i * 4096);               \
      gload16(w2p + boff[i] + (kb) + csw, dB + i * 4096);              \
    }                                                                  \
  } while (0)

  asm volatile("s_waitcnt vmcnt(0)" ::: "memory");
  STAGE2(0, kbase);

  int cur = 0;
  const int NKT = F_DIM / 64 / 2;             // 22 K-tiles per half
  for (int kt = 0; kt < NKT; ++kt) {
    if (kt < NKT - 1) {
      STAGE2(cur ^ 1, kbase + (kt + 1) * 128);
      asm volatile("s_waitcnt vmcnt(8)" ::: "memory");
    } else {
      asm volatile("s_waitcnt vmcnt(0)" ::: "memory");
    }
    __syncthreads();
    const char* rA = sA + cur * 16384;
    const char* rB = sB + cur * 16384;
#pragma unroll
    for (int kk = 0; kk < 2; ++kk) {
      const int colb = kk * 64 + (lane >> 4) * 16;
      bf16x8 af[4], bx[4];
#pragma unroll
      for (int m = 0; m < 4; ++m)
        af[m] = *(const bf16x8*)(rA + swz(wrow + m * 16 + (lane & 15), colb));
#pragma unroll
      for (int n = 0; n < 4; ++n)
        bx[n] = *(const bf16x8*)(rB + swz(wcol + n * 16 + (lane & 15), colb));
#pragma unroll
      for (int m = 0; m < 4; ++m)
#pragma unroll
        for (int n = 0; n < 4; ++n)
          acc[m][n] = __builtin_amdgcn_mfma_f32_16x16x32_bf16(
              af[m], bx[n], acc[m][n], 0, 0, 0);
    }
    __syncthreads();
    cur ^= 1;
  }
#undef STAGE2

  // slot space per half = 2*T_TOK rows (8192 token-expert slots)
  __hip_bfloat16* yh = y + (size_t)kh * (2 * T_TOK) * H_DIM;
#pragma unroll
  for (int m = 0; m < 4; ++m) {
#pragma unroll
    for (int q = 0; q < 4; ++q) {
      int pos = tm * 128 + wrow + m * 16 + ((lane >> 4) << 2) + q;
      if (pos < n_e) {
        __hip_bfloat16* yrow = yh + (size_t)(off_e + pos) * H_DIM + n0;
#pragma unroll
        for (int n = 0; n < 4; ++n)
          yrow[wcol + n * 16 + (lane & 15)] = __float2bfloat16(acc[m][n][q]);
      }
    }
  }
}

// ------------- combine: out[t] = w0*(y0+y1)[slot0] + (1-w0)*(y0+y1)[slot1] --
__global__ __launch_bounds__(256) void combine_kernel(
    const __hip_bfloat16* __restrict__ y, const int* __restrict__ counts,
    const int* __restrict__ meta0, const int* __restrict__ meta1,
    const float* __restrict__ wcomb, float* __restrict__ out)
{
  const int t = blockIdx.x;
  const int m0 = meta0[t], m1 = meta1[t];
  const int i0 = m0 >> 16, i1 = m1 >> 16;
  int o0 = 0, o1 = 0;
#pragma unroll
  for (int i = 0; i < E_NUM; ++i) {
    int c = counts[i];
    o0 += (i < i0) ? c : 0;
    o1 += (i < i1) ? c : 0;
  }
  const float w0 = wcomb[t];
  const float w1 = 1.f - w0;
  const size_t s0 = (size_t)(o0 + (m0 & 0xffff)) * H_DIM;
  const size_t s1 = (size_t)(o1 + (m1 & 0xffff)) * H_DIM;
  const size_t HB = (size_t)(2 * T_TOK) * H_DIM;  // second K-half offset
  const int c = threadIdx.x * 4;
  ushort4 a0 = *(const ushort4*)(y + s0 + c);
  ushort4 a1 = *(const ushort4*)(y + HB + s0 + c);
  ushort4 b0 = *(const ushort4*)(y + s1 + c);
  ushort4 b1 = *(const ushort4*)(y + HB + s1 + c);
  float4 o;
  o.x = w0 * (b2f(a0.x) + b2f(a1.x)) + w1 * (b2f(b0.x) + b2f(b1.x));
  o.y = w0 * (b2f(a0.y) + b2f(a1.y)) + w1 * (b2f(b0.y) + b2f(b1.y));
  o.z = w0 * (b2f(a0.z) + b2f(a1.z)) + w1 * (b2f(b0.z) + b2f(b1.z));
  o.w = w0 * (b2f(a0.w) + b2f(a1.w)) + w1 * (b2f(b0.w) + b2f(b1.w));
  *(float4*)(out + (size_t)t * H_DIM + c) = o;
}

// =================== fallback path (round-1-proven kernels) ================
__global__ __launch_bounds__(256) void router_fb(
    const float* __restrict__ x, const float* __restrict__ gate,
    float* __restrict__ logits_out, __hip_bfloat16* __restrict__ xb,
    int* __restrict__ counts, int* __restrict__ idx_list,
    float* __restrict__ wgt_list)
{
  const int wv = threadIdx.x >> 6;
  const int lane = threadIdx.x & 63;
  const int t = blockIdx.x * 4 + wv;
  const float4* xr = (const float4*)(x + (size_t)t * H_DIM);
  const float4* g4 = (const float4*)gate;
  float acc[E_NUM];
#pragma unroll
  for (int e = 0; e < E_NUM; ++e) acc[e] = 0.f;
  unsigned* xbo = (unsigned*)(xb + (size_t)t * H_DIM);
#pragma unroll
  for (int j = 0; j < 4; ++j) {
    int i = j * 64 + lane;
    float4 xv = xr[i];
    uint2 pk;
    pk.x = pack2bf16(xv.x, xv.y);
    pk.y = pack2bf16(xv.z, xv.w);
    *(uint2*)(xbo + i * 2) = pk;
#pragma unroll
    for (int e = 0; e < E_NUM; ++e) {
      float4 gv = g4[e * 256 + i];
      acc[e] += xv.x * gv.x + xv.y * gv.y + xv.z * gv.z + xv.w * gv.w;
    }
  }
#pragma unroll
  for (int off = 32; off > 0; off >>= 1) {
#pragma unroll
    for (int e = 0; e < E_NUM; ++e) acc[e] += __shfl_xor(acc[e], off, 64);
  }
  if (lane == 0) {
#pragma unroll
    for (int e = 0; e < E_NUM; ++e) logits_out[(size_t)t * E_NUM + e] = acc[e];
    int i0 = 0; float v0 = acc[0];
#pragma unroll
    for (int e = 1; e < E_NUM; ++e) if (acc[e] > v0) { v0 = acc[e]; i0 = e; }
    int i1 = -1; float v1 = -1e30f;
#pragma unroll
    for (int e = 0; e < E_NUM; ++e)
      if (e != i0 && acc[e] > v1) { v1 = acc[e]; i1 = e; }
    float p1 = __expf(v1 - v0);
    float w0 = 1.f / (1.f + p1);
    float w1 = p1 / (1.f + p1);
    int pos0 = atomicAdd(&counts[i0], 1);
    idx_list[i0 * T_TOK + pos0] = t;
    wgt_list[i0 * T_TOK + pos0] = w0;
    int pos1 = atomicAdd(&counts[i1], 1);
    idx_list[i1 * T_TOK + pos1] = t;
    wgt_list[i1 * T_TOK + pos1] = w1;
  }
}

__global__ __launch_bounds__(256) void gemm1_fb(
    const __hip_bfloat16* __restrict__ xb,
    const float* __restrict__ w1, const float* __restrict__ w3,
    const int* __restrict__ counts, const int* __restrict__ idx_list,
    __hip_bfloat16* __restrict__ hidden)
{
  const int e = blockIdx.z;
  const int n_e = counts[e];
  const int tm = blockIdx.y;
  if (n_e == 0 || tm * 128 >= n_e) return;
  const int tn = blockIdx.x;
  const int f0 = tn * 128;
  const int off_e = prefix_off(counts, e);

  __shared__ short sA[128 * 64];
  __shared__ short sB1[128 * 64];
  __shared__ short sB3[128 * 64];
  __shared__ int s_row[128];

  const int tid = threadIdx.x;
  if (tid < 128) {
    int pos = tm * 128 + tid;
    int p = pos < n_e ? pos : n_e - 1;
    s_row[tid] = idx_list[e * T_TOK + p];
  }
  const int lane = tid & 63;
  const int wv = tid >> 6;
  const int wrow = (wv >> 1) * 64;
  const int wcol = (wv & 1) * 64;
  const int cc = tid & 7;
  const int rbase = tid >> 3;

  floatx4 acc1[4][4], acc3[4][4];
#pragma unroll
  for (int m = 0; m < 4; ++m)
#pragma unroll
    for (int n = 0; n < 4; ++n)
#pragma unroll
      for (int q = 0; q < 4; ++q) { acc1[m][n][q] = 0.f; acc3[m][n][q] = 0.f; }

  const float* w1e = w1 + (size_t)e * F_DIM * H_DIM + (size_t)f0 * H_DIM;
  const float* w3e = w3 + (size_t)e * F_DIM * H_DIM + (size_t)f0 * H_DIM;

  for (int kt = 0; kt < H_DIM / 64; ++kt) {
    const int k0 = kt * 64;
    __syncthreads();
#pragma unroll
    for (int i = 0; i < 4; ++i) {
      int rr = rbase + 32 * i;
      uint4 av = *(const uint4*)(xb + (size_t)s_row[rr] * H_DIM + k0 + cc * 8);
      *(uint4*)((char*)sA + swz(rr, cc * 16)) = av;
      const float4* p1 = (const float4*)(w1e + (size_t)rr * H_DIM + k0 + cc * 8);
      float4 a1 = p1[0], b1 = p1[1];
      uint4 pb1;
      pb1.x = pack2bf16(a1.x, a1.y); pb1.y = pack2bf16(a1.z, a1.w);
      pb1.z = pack2bf16(b1.x, b1.y); pb1.w = pack2bf16(b1.z, b1.w);
      *(uint4*)((char*)sB1 + swz(rr, cc * 16)) = pb1;
      const float4* p3 = (const float4*)(w3e + (size_t)rr * H_DIM + k0 + cc * 8);
      float4 a3 = p3[0], b3 = p3[1];
      uint4 pb3;
      pb3.x = pack2bf16(a3.x, a3.y); pb3.y = pack2bf16(a3.z, a3.w);
      pb3.z = pack2bf16(b3.x, b3.y); pb3.w = pack2bf16(b3.z, b3.w);
      *(uint4*)((char*)sB3 + swz(rr, cc * 16)) = pb3;
    }
    __syncthreads();
#pragma unroll
    for (int kk = 0; kk < 2; ++kk) {
      const int colb = kk * 64 + (lane >> 4) * 16;
      bf16x8 af[4], bf1[4], bf3[4];
#pragma unroll
      for (int m = 0; m < 4; ++m)
        af[m] = *(const bf16x8*)((const char*)sA +
                                 swz(wrow + m * 16 + (lane & 15), colb));
#pragma unroll
      for (int n = 0; n < 4; ++n) {
        bf1[n] = *(const bf16x8*)((const char*)sB1 +
                                  swz(wcol + n * 16 + (lane & 15), colb));
        bf3[n] = *(const bf16x8*)((const char*)sB3 +
                                  swz(wcol + n * 16 + (lane & 15), colb));
      }
#pragma unroll
      for (int m = 0; m < 4; ++m)
#pragma unroll
        for (int n = 0; n < 4; ++n) {
          acc1[m][n] = __builtin_amdgcn_mfma_f32_16x16x32_bf16(
              af[m], bf1[n], acc1[m][n], 0, 0, 0);
          acc3[m][n] = __builtin_amdgcn_mfma_f32_16x16x32_bf16(
              af[m], bf3[n], acc3[m][n], 0, 0, 0);
        }
    }
  }
#pragma unroll
  for (int m = 0; m < 4; ++m) {
#pragma unroll
    for (int q = 0; q < 4; ++q) {
      int rl = wrow + m * 16 + ((lane >> 4) << 2) + q;
      int pos = tm * 128 + rl;
      if (pos < n_e) {
        __hip_bfloat16* hrow = hidden + (size_t)(off_e + pos) * F_DIM + f0;
#pragma unroll
        for (int n = 0; n < 4; ++n) {
          float h1 = acc1[m][n][q];
          float h3 = acc3[m][n][q];
          float h = (h1 / (1.f + __expf(-h1))) * h3;
          hrow[wcol + n * 16 + (lane & 15)] = __float2bfloat16(h);
        }
      }
    }
  }
}

__global__ __launch_bounds__(256) void gemm2_fb(
    const __hip_bfloat16* __restrict__ hidden, const float* __restrict__ w2,
    const int* __restrict__ counts, const int* __restrict__ idx_list,
    const float* __restrict__ wgt_list, float* __restrict__ out)
{
  const int e = blockIdx.z;
  const int n_e = counts[e];
  const int tm = blockIdx.y;
  if (n_e == 0 || tm * 128 >= n_e) return;
  const int tn = blockIdx.x;
  const int n0 = tn * 128;
  const int off_e = prefix_off(counts, e);

  __shared__ short sA[128 * 64];
  __shared__ short sB[128 * 64];
  __shared__ int s_tok[128];
  __shared__ float s_wgt[128];

  const int tid = threadIdx.x;
  if (tid < 128) {
    int pos = tm * 128 + tid;
    if (pos < n_e) {
      s_tok[tid] = idx_list[e * T_TOK + pos];
      s_wgt[tid] = wgt_list[e * T_TOK + pos];
    } else {
      s_tok[tid] = -1;
      s_wgt[tid] = 0.f;
    }
  }
  const int lane = tid & 63;
  const int wv = tid >> 6;
  const int wrow = (wv >> 1) * 64;
  const int wcol = (wv & 1) * 64;
  const int cc = tid & 7;
  const int rbase = tid >> 3;

  floatx4 acc[4][4];
#pragma unroll
  for (int m = 0; m < 4; ++m)
#pragma unroll
    for (int n = 0; n < 4; ++n)
#pragma unroll
      for (int q = 0; q < 4; ++q) acc[m][n][q] = 0.f;

  const float* w2e = w2 + (size_t)e * H_DIM * F_DIM + (size_t)n0 * F_DIM;

  for (int kt = 0; kt < F_DIM / 64; ++kt) {
    const int k0 = kt * 64;
    __syncthreads();
#pragma unroll
    for (int i = 0; i < 4; ++i) {
      int rr = rbase + 32 * i;
      int pos = tm * 128 + rr;
      int pr = pos < n_e ? pos : n_e - 1;
      uint4 av = *(const uint4*)(hidden + (size_t)(off_e + pr) * F_DIM +
                                 k0 + cc * 8);
      *(uint4*)((char*)sA + swz(rr, cc * 16)) = av;
      const float4* pb = (const float4*)(w2e + (size_t)rr * F_DIM + k0 + cc * 8);
      float4 ba = pb[0], bb = pb[1];
      uint4 pk;
      pk.x = pack2bf16(ba.x, ba.y); pk.y = pack2bf16(ba.z, ba.w);
      pk.z = pack2bf16(bb.x, bb.y); pk.w = pack2bf16(bb.z, bb.w);
      *(uint4*)((char*)sB + swz(rr, cc * 16)) = pk;
    }
    __syncthreads();
#pragma unroll
    for (int kk = 0; kk < 2; ++kk) {
      const int colb = kk * 64 + (lane >> 4) * 16;
      bf16x8 af[4], bf[4];
#pragma unroll
      for (int m = 0; m < 4; ++m)
        af[m] = *(const bf16x8*)((const char*)sA +
                                 swz(wrow + m * 16 + (lane & 15), colb));
#pragma unroll
      for (int n = 0; n < 4; ++n)
        bf[n] = *(const bf16x8*)((const char*)sB +
                                 swz(wcol + n * 16 + (lane & 15), colb));
#pragma unroll
      for (int m = 0; m < 4; ++m)
#pragma unroll
        for (int n = 0; n < 4; ++n)
          acc[m][n] = __builtin_amdgcn_mfma_f32_16x16x32_bf16(
              af[m], bf[n], acc[m][n], 0, 0, 0);
    }
  }
#pragma unroll
  for (int m = 0; m < 4; ++m) {
#pragma unroll
    for (int q = 0; q < 4; ++q) {
      int rl = wrow + m * 16 + ((lane >> 4) << 2) + q;
      int tok = s_tok[rl];
      if (tok >= 0) {
        float wgt = s_wgt[rl];
        float* orow = out + (size_t)tok * H_DIM + n0;
#pragma unroll
        for (int n = 0; n < 4; ++n)
          atomicAdd(&orow[wcol + n * 16 + (lane & 15)], wgt * acc[m][n][q]);
      }
    }
  }
}

extern "C" void kernel_launch(void* const* d_in, const int* in_sizes, int n_in,
                              void* d_out, int out_size, void* d_ws,
                              size_t ws_size, hipStream_t stream) {
  const float* x = (const float*)d_in[0];
  const float* gate = (const float*)d_in[1];
  const float* w1 = (const float*)d_in[2];
  const float* w3 = (const float*)d_in[3];
  const float* w2 = (const float*)d_in[4];

  float* out = (float*)d_out;                        // [T, H]
  float* logits = out + (size_t)T_TOK * H_DIM;       // [T, E]

  char* ws = (char*)d_ws;
  const size_t o_idx = 256;
  const size_t o_wgt = o_idx + (size_t)E_NUM * T_TOK * 4;
  const size_t o_m0  = o_wgt + (size_t)E_NUM * T_TOK * 4;
  const size_t o_m1  = o_m0 + (size_t)T_TOK * 4;
  const size_t o_wc  = o_m1 + (size_t)T_TOK * 4;
  const size_t o_xb  = o_wc + (size_t)T_TOK * 4;
  const size_t o_hid = o_xb + (size_t)T_TOK * H_DIM * 2;
  const size_t o_wB  = o_hid + (size_t)2 * T_TOK * F_DIM * 2;
  const size_t o_w2b = o_wB + (size_t)E_NUM * 2 * F_DIM * H_DIM * 2;
  const size_t need  = o_w2b + (size_t)E_NUM * H_DIM * F_DIM * 2;  // ~184 MiB

  int* counts = (int*)ws;
  int* idx_list = (int*)(ws + o_idx);
  float* wgt_list = (float*)(ws + o_wgt);
  int* meta0 = (int*)(ws + o_m0);
  int* meta1 = (int*)(ws + o_m1);
  float* wcomb = (float*)(ws + o_wc);
  __hip_bfloat16* xb = (__hip_bfloat16*)(ws + o_xb);
  __hip_bfloat16* hidden = (__hip_bfloat16*)(ws + o_hid);

  hipMemsetAsync(counts, 0, 64, stream);

  if (ws_size >= need) {
    __hip_bfloat16* wB = (__hip_bfloat16*)(ws + o_wB);
    __hip_bfloat16* w2b = (__hip_bfloat16*)(ws + o_w2b);
    __hip_bfloat16* y = (__hip_bfloat16*)(ws + o_wB);   // alias: wB dead then
                                                        // (2 halves = 34 MB)

    prep_kernel<<<NB_W13 + NB_W2 + NB_RT, 256, 0, stream>>>(
        w1, w3, w2, x, gate, wB, w2b, logits, xb, counts, idx_list, wgt_list,
        meta0, meta1, wcomb);
    gemm1_kernel<<<dim3(2 * F_DIM / 256, T_TOK / 256, E_NUM), 512, 0,
                   stream>>>(xb, wB, counts, idx_list, hidden);
    gemm2_kernel<<<dim3(8, 32, 2 * E_NUM), 256, 0, stream>>>(
        hidden, w2b, counts, y);
    combine_kernel<<<T_TOK, 256, 0, stream>>>(y, counts, meta0, meta1, wcomb,
                                              out);
  } else {
    hipMemsetAsync(out, 0, (size_t)T_TOK * H_DIM * sizeof(float), stream);
    router_fb<<<T_TOK / 4, 256, 0, stream>>>(x, gate, logits, xb, counts,
                                             idx_list, wgt_list);
    gemm1_fb<<<dim3(F_DIM / 128, T_TOK / 128, E_NUM), 256, 0, stream>>>(
        xb, w1, w3, counts, idx_list, hidden);
    gemm2_fb<<<dim3(H_DIM / 128, T_TOK / 128, E_NUM), 256, 0, stream>>>(
        hidden, w2, counts, idx_list, wgt_list, out);
  }
}

// Round 17
// 426.015 us; speedup vs baseline: 1.0657x; 1.0467x over previous
//
#include <hip/hip_runtime.h>
#include <hip/hip_bf16.h>
#include <stdint.h>

#define T_TOK 4096
#define H_DIM 1024
#define F_DIM 2816
#define E_NUM 8

typedef __attribute__((ext_vector_type(8))) __bf16 bf16x8;
typedef __attribute__((ext_vector_type(4))) float floatx4;
typedef __attribute__((address_space(3))) char lds_char;
typedef __attribute__((address_space(1))) const char glb_char;

// async 16B global->LDS (dest = wave-uniform base + lane*16)
__device__ __forceinline__ void gload16(const void* g, void* l) {
  __builtin_amdgcn_global_load_lds((glb_char*)g, (lds_char*)l, 16, 0, 0);
}

// round-to-nearest-even fp32 -> bf16, packed 2-at-a-time
__device__ __forceinline__ unsigned pack2bf16(float a, float b) {
  unsigned ua = __builtin_bit_cast(unsigned, a);
  unsigned ub = __builtin_bit_cast(unsigned, b);
  ua += 0x7fffu + ((ua >> 16) & 1u);
  ub += 0x7fffu + ((ub >> 16) & 1u);
  return (ua >> 16) | (ub & 0xffff0000u);
}

__device__ __forceinline__ float b2f(unsigned short u) {
  unsigned v = ((unsigned)u) << 16;
  return __builtin_bit_cast(float, v);
}

// XOR swizzle for [row][64 bf16] LDS tiles (128 B rows): proven 0-conflict.
__device__ __forceinline__ int swz(int row, int colb) {
  return (row * 128 + colb) ^ ((row & 7) << 4);
}

// inline exclusive-prefix of counts[0..7] below expert e (branchless, no array)
__device__ __forceinline__ int prefix_off(const int* __restrict__ counts,
                                          int e) {
  int o = 0;
#pragma unroll
  for (int i = 0; i < E_NUM; ++i) o += (i < e) ? counts[i] : 0;
  return o;
}

// ---------------- merged prep: w13 convert | w2 convert | router ------------
// blocks [0, 22528): w13 interleaved convert -> wB[e][rho][h]
//   rho in 32-row groups of [16 w1-rows | 16 w3-rows]; f=(rho>>5)*16+(rho&15)
// blocks [22528, 33792): w2 fp32->bf16 convert (exact cover)
// blocks [33792, 34816): router (4 tokens per block)
#define NB_W13 (F_DIM * E_NUM)
#define NB_W2  (E_NUM * F_DIM * H_DIM / 8 / 256)
#define NB_RT  (T_TOK / 4)
__global__ __launch_bounds__(256) void prep_kernel(
    const float* __restrict__ w1, const float* __restrict__ w3,
    const float* __restrict__ w2f, const float* __restrict__ x,
    const float* __restrict__ gate, __hip_bfloat16* __restrict__ wB,
    __hip_bfloat16* __restrict__ w2b, float* __restrict__ logits_out,
    __hip_bfloat16* __restrict__ xb, int* __restrict__ counts,
    int* __restrict__ idx_list, float* __restrict__ wgt_list,
    int* __restrict__ meta0, int* __restrict__ meta1,
    float* __restrict__ wcomb)
{
  const int bid = blockIdx.x;
  if (bid < NB_W13) {
    const int e = bid / F_DIM;
    const int bx = bid - e * F_DIM;
    const int rho = bx * 2 + (threadIdx.x >> 7);
    const int hc = threadIdx.x & 127;               // 8-float chunk in row
    const int f = ((rho >> 5) << 4) + (rho & 15);
    const float* src = ((rho >> 4) & 1 ? w3 : w1) +
                       ((size_t)e * F_DIM + f) * H_DIM + hc * 8;
    const float4* s = (const float4*)src;
    float4 a = s[0], b = s[1];
    uint4 p;
    p.x = pack2bf16(a.x, a.y); p.y = pack2bf16(a.z, a.w);
    p.z = pack2bf16(b.x, b.y); p.w = pack2bf16(b.z, b.w);
    *(uint4*)((char*)wB +
              (((size_t)e * (2 * F_DIM) + rho) * H_DIM + hc * 8) * 2) = p;
    return;
  }
  if (bid < NB_W13 + NB_W2) {
    const size_t i = (size_t)(bid - NB_W13) * 256 + threadIdx.x;  // chunk8
    const float4* s = (const float4*)(w2f + i * 8);
    float4 a = s[0], b = s[1];
    uint4 p;
    p.x = pack2bf16(a.x, a.y); p.y = pack2bf16(a.z, a.w);
    p.z = pack2bf16(b.x, b.y); p.w = pack2bf16(b.z, b.w);
    *(uint4*)((char*)w2b + i * 16) = p;
    return;
  }
  // ------- router section -------
  const int blk = bid - (NB_W13 + NB_W2);
  const int wv = threadIdx.x >> 6;
  const int lane = threadIdx.x & 63;
  const int t = blk * 4 + wv;

  const float4* xr = (const float4*)(x + (size_t)t * H_DIM);
  const float4* g4 = (const float4*)gate;

  float acc[E_NUM];
#pragma unroll
  for (int e = 0; e < E_NUM; ++e) acc[e] = 0.f;

  unsigned* xbo = (unsigned*)(xb + (size_t)t * H_DIM);
#pragma unroll
  for (int j = 0; j < 4; ++j) {
    int i = j * 64 + lane;
    float4 xv = xr[i];
    uint2 pk;
    pk.x = pack2bf16(xv.x, xv.y);
    pk.y = pack2bf16(xv.z, xv.w);
    *(uint2*)(xbo + i * 2) = pk;
#pragma unroll
    for (int e = 0; e < E_NUM; ++e) {
      float4 gv = g4[e * 256 + i];
      acc[e] += xv.x * gv.x + xv.y * gv.y + xv.z * gv.z + xv.w * gv.w;
    }
  }
#pragma unroll
  for (int off = 32; off > 0; off >>= 1) {
#pragma unroll
    for (int e = 0; e < E_NUM; ++e) acc[e] += __shfl_xor(acc[e], off, 64);
  }

  if (lane == 0) {
#pragma unroll
    for (int e = 0; e < E_NUM; ++e) logits_out[(size_t)t * E_NUM + e] = acc[e];
    int i0 = 0; float v0 = acc[0];
#pragma unroll
    for (int e = 1; e < E_NUM; ++e) if (acc[e] > v0) { v0 = acc[e]; i0 = e; }
    int i1 = -1; float v1 = -1e30f;
#pragma unroll
    for (int e = 0; e < E_NUM; ++e)
      if (e != i0 && acc[e] > v1) { v1 = acc[e]; i1 = e; }
    float p1 = __expf(v1 - v0);
    float w0 = 1.f / (1.f + p1);
    float w1 = p1 / (1.f + p1);
    int pos0 = atomicAdd(&counts[i0], 1);
    idx_list[i0 * T_TOK + pos0] = t;
    wgt_list[i0 * T_TOK + pos0] = w0;
    int pos1 = atomicAdd(&counts[i1], 1);
    idx_list[i1 * T_TOK + pos1] = t;
    wgt_list[i1 * T_TOK + pos1] = w1;
    meta0[t] = (i0 << 16) | pos0;
    meta1[t] = (i1 << 16) | pos1;
    wcomb[t] = w0;
  }
}

// ------------- GEMM1: 256x256 tile, 8 waves, BK=64, 2-phase counted vmcnt ---
// R5-proven structure (189 us). C = X @ wB^T over interleaved wB;
// silu(even frag)*odd frag in epilogue. Offsets computed inline from counts.
__global__ __launch_bounds__(512, 2) void gemm1_kernel(
    const __hip_bfloat16* __restrict__ xb,
    const __hip_bfloat16* __restrict__ wB,
    const int* __restrict__ counts, const int* __restrict__ idx_list,
    __hip_bfloat16* __restrict__ hidden)
{
  const int e = blockIdx.z;
  const int n_e = counts[e];
  const int tm = blockIdx.y;
  if (n_e == 0 || tm * 256 >= n_e) return;
  const int tn = blockIdx.x;                  // 256 wB rows = 128 f
  const int off_e = prefix_off(counts, e);

  __shared__ char lds[131072];
  char* sA = lds;                             // 2 x 32768
  char* sB = lds + 65536;                     // 2 x 32768

  const int tid = threadIdx.x;
  const int lane = tid & 63;
  const int wv = tid >> 6;                    // 0..7
  const int wrow = (wv >> 2) * 128;           // {0,128}
  const int wcol = (wv & 3) * 64;             // {0,64,128,192}
  const int csw = ((lane & 7) ^ (lane >> 3)) << 4;
  const int wvb = wv * 1024;

  size_t aoff[4];
#pragma unroll
  for (int i = 0; i < 4; ++i) {
    int rr = i * 64 + wv * 8 + (lane >> 3);
    int pos = tm * 256 + rr;
    int p = pos < n_e ? pos : n_e - 1;
    aoff[i] = (size_t)idx_list[e * T_TOK + p] * 2048;
  }
  const char* xbp = (const char*)xb;
  const char* wBp =
      (const char*)wB + ((size_t)e * (2 * F_DIM) + tn * 256) * 2048;
  size_t boff[4];
#pragma unroll
  for (int i = 0; i < 4; ++i)
    boff[i] = (size_t)(i * 64 + wv * 8 + (lane >> 3)) * 2048;

  floatx4 acc[8][4];
#pragma unroll
  for (int m = 0; m < 8; ++m)
#pragma unroll
    for (int n = 0; n < 4; ++n)
#pragma unroll
      for (int q = 0; q < 4; ++q) acc[m][n][q] = 0.f;

#define STAGE1(set, kb)                                                \
  do {                                                                 \
    char* dA = sA + (set) * 32768 + wvb;                               \
    char* dB = sB + (set) * 32768 + wvb;                               \
    _Pragma("unroll")                                                  \
    for (int i = 0; i < 4; ++i) {                                      \
      gload16(xbp + aoff[i] + (kb) + csw, dA + i * 8192);              \
      gload16(wBp + boff[i] + (kb) + csw, dB + i * 8192);              \
    }                                                                  \
  } while (0)

  // drain gather loads so counted vmcnt sees only our DMAs
  asm volatile("s_waitcnt vmcnt(0)" ::: "memory");
  STAGE1(0, 0);

  int cur = 0;
  for (int kt = 0; kt < H_DIM / 64; ++kt) {       // 16 K-tiles
    if (kt < H_DIM / 64 - 1) {
      STAGE1(cur ^ 1, (kt + 1) * 128);
      asm volatile("s_waitcnt vmcnt(8)" ::: "memory");  // this tile landed
    } else {
      asm volatile("s_waitcnt vmcnt(0)" ::: "memory");
    }
    __syncthreads();
    const char* rA = sA + cur * 32768;
    const char* rB = sB + cur * 32768;
#pragma unroll
    for (int kk = 0; kk < 2; ++kk) {
      const int colb = kk * 64 + (lane >> 4) * 16;
      bf16x8 af[8], bx[4];
#pragma unroll
      for (int m = 0; m < 8; ++m)
        af[m] = *(const bf16x8*)(rA + swz(wrow + m * 16 + (lane & 15), colb));
#pragma unroll
      for (int n = 0; n < 4; ++n)
        bx[n] = *(const bf16x8*)(rB + swz(wcol + n * 16 + (lane & 15), colb));
#pragma unroll
      for (int m = 0; m < 8; ++m)
#pragma unroll
        for (int n = 0; n < 4; ++n)
          acc[m][n] = __builtin_amdgcn_mfma_f32_16x16x32_bf16(
              af[m], bx[n], acc[m][n], 0, 0, 0);
    }
    __syncthreads();
    cur ^= 1;
  }
#undef STAGE1

  // epilogue: pair even/odd N-fragments (w1/w3 of same f-block), silu*mul
  const int fbase = (tn * 8 + (wcol >> 5)) * 16 + (lane & 15);
#pragma unroll
  for (int m = 0; m < 8; ++m) {
#pragma unroll
    for (int q = 0; q < 4; ++q) {
      int pos = tm * 256 + wrow + m * 16 + ((lane >> 4) << 2) + q;
      if (pos < n_e) {
        __hip_bfloat16* hrow = hidden + (size_t)(off_e + pos) * F_DIM;
#pragma unroll
        for (int j = 0; j < 2; ++j) {
          float h1 = acc[m][2 * j][q];
          float h3 = acc[m][2 * j + 1][q];
          float h = (h1 / (1.f + __expf(-h1))) * h3;   // silu(h1)*h3
          hrow[fbase + j * 16] = __float2bfloat16(h);
        }
      }
    }
  }
}

// ------------- GEMM2: 128x128 tile, split-K x2, 2-phase counted vmcnt -------
// bz = e + 8*khalf; bf16 partials in y[khalf] (slot space 2*T_TOK rows each).
__global__ __launch_bounds__(256, 2) void gemm2_kernel(
    const __hip_bfloat16* __restrict__ hidden,
    const __hip_bfloat16* __restrict__ w2b,
    const int* __restrict__ counts, __hip_bfloat16* __restrict__ y)
{
  const int e = blockIdx.z & 7;
  const int kh = blockIdx.z >> 3;             // K-half 0/1
  const int tm = blockIdx.y;                  // 0..31
  const int tn = blockIdx.x;                  // 0..7
  const int n_e = counts[e];
  if (n_e == 0 || tm * 128 >= n_e) return;
  const int n0 = tn * 128;
  const int off_e = prefix_off(counts, e);
  const int kbase = kh * (F_DIM);             // byte base = kh*22*128

  __shared__ char lds[65536];
  char* sA = lds;                             // 2 x 16384
  char* sB = lds + 32768;                     // 2 x 16384

  const int tid = threadIdx.x;
  const int lane = tid & 63;
  const int wv = tid >> 6;
  const int wrow = (wv >> 1) * 64;
  const int wcol = (wv & 1) * 64;
  const int csw = ((lane & 7) ^ (lane >> 3)) << 4;
  const int wvb = wv * 1024;

  size_t aoff[4], boff[4];
#pragma unroll
  for (int i = 0; i < 4; ++i) {
    int rr = i * 32 + wv * 8 + (lane >> 3);
    int pos = tm * 128 + rr;
    int p = pos < n_e ? pos : n_e - 1;
    aoff[i] = (size_t)(off_e + p) * (F_DIM * 2);
    boff[i] = ((size_t)e * H_DIM + n0 + rr) * (F_DIM * 2);
  }
  const char* hp = (const char*)hidden;
  const char* w2p = (const char*)w2b;

  floatx4 acc[4][4];
#pragma unroll
  for (int m = 0; m < 4; ++m)
#pragma unroll
    for (int n = 0; n < 4; ++n)
#pragma unroll
      for (int q = 0; q < 4; ++q) acc[m][n][q] = 0.f;

#define STAGE2(set, kb)                                                \
  do {                                                                 \
    char* dA = sA + (set) * 16384 + wvb;                               \
    char* dB = sB + (set) * 16384 + wvb;                               \
    _Pragma("unroll")                                                  \
    for (int i = 0; i < 4; ++i) {                                      \
      gload16(hp + aoff[i] + (kb) + csw, dA + i * 4096);               \
      gload16(w2p + boff[i] + (kb) + csw, dB + i * 4096);              \
    }                                                                  \
  } while (0)

  asm volatile("s_waitcnt vmcnt(0)" ::: "memory");
  STAGE2(0, kbase);

  int cur = 0;
  const int NKT = F_DIM / 64 / 2;             // 22 K-tiles per half
  for (int kt = 0; kt < NKT; ++kt) {
    if (kt < NKT - 1) {
      STAGE2(cur ^ 1, kbase + (kt + 1) * 128);
      asm volatile("s_waitcnt vmcnt(8)" ::: "memory");
    } else {
      asm volatile("s_waitcnt vmcnt(0)" ::: "memory");
    }
    __syncthreads();
    const char* rA = sA + cur * 16384;
    const char* rB = sB + cur * 16384;
#pragma unroll
    for (int kk = 0; kk < 2; ++kk) {
      const int colb = kk * 64 + (lane >> 4) * 16;
      bf16x8 af[4], bx[4];
#pragma unroll
      for (int m = 0; m < 4; ++m)
        af[m] = *(const bf16x8*)(rA + swz(wrow + m * 16 + (lane & 15), colb));
#pragma unroll
      for (int n = 0; n < 4; ++n)
        bx[n] = *(const bf16x8*)(rB + swz(wcol + n * 16 + (lane & 15), colb));
#pragma unroll
      for (int m = 0; m < 4; ++m)
#pragma unroll
        for (int n = 0; n < 4; ++n)
          acc[m][n] = __builtin_amdgcn_mfma_f32_16x16x32_bf16(
              af[m], bx[n], acc[m][n], 0, 0, 0);
    }
    __syncthreads();
    cur ^= 1;
  }
#undef STAGE2

  // slot space per half = 2*T_TOK rows (8192 token-expert slots)
  __hip_bfloat16* yh = y + (size_t)kh * (2 * T_TOK) * H_DIM;
#pragma unroll
  for (int m = 0; m < 4; ++m) {
#pragma unroll
    for (int q = 0; q < 4; ++q) {
      int pos = tm * 128 + wrow + m * 16 + ((lane >> 4) << 2) + q;
      if (pos < n_e) {
        __hip_bfloat16* yrow = yh + (size_t)(off_e + pos) * H_DIM + n0;
#pragma unroll
        for (int n = 0; n < 4; ++n)
          yrow[wcol + n * 16 + (lane & 15)] = __float2bfloat16(acc[m][n][q]);
      }
    }
  }
}

// ------------- combine: out[t] = w0*(y0+y1)[slot0] + (1-w0)*(y0+y1)[slot1] --
__global__ __launch_bounds__(256) void combine_kernel(
    const __hip_bfloat16* __restrict__ y, const int* __restrict__ counts,
    const int* __restrict__ meta0, const int* __restrict__ meta1,
    const float* __restrict__ wcomb, float* __restrict__ out)
{
  const int t = blockIdx.x;
  const int m0 = meta0[t], m1 = meta1[t];
  const int i0 = m0 >> 16, i1 = m1 >> 16;
  int o0 = 0, o1 = 0;
#pragma unroll
  for (int i = 0; i < E_NUM; ++i) {
    int c = counts[i];
    o0 += (i < i0) ? c : 0;
    o1 += (i < i1) ? c : 0;
  }
  const float w0 = wcomb[t];
  const float w1 = 1.f - w0;
  const size_t s0 = (size_t)(o0 + (m0 & 0xffff)) * H_DIM;
  const size_t s1 = (size_t)(o1 + (m1 & 0xffff)) * H_DIM;
  const size_t HB = (size_t)(2 * T_TOK) * H_DIM;  // second K-half offset
  const int c = threadIdx.x * 4;
  ushort4 a0 = *(const ushort4*)(y + s0 + c);
  ushort4 a1 = *(const ushort4*)(y + HB + s0 + c);
  ushort4 b0 = *(const ushort4*)(y + s1 + c);
  ushort4 b1 = *(const ushort4*)(y + HB + s1 + c);
  float4 o;
  o.x = w0 * (b2f(a0.x) + b2f(a1.x)) + w1 * (b2f(b0.x) + b2f(b1.x));
  o.y = w0 * (b2f(a0.y) + b2f(a1.y)) + w1 * (b2f(b0.y) + b2f(b1.y));
  o.z = w0 * (b2f(a0.z) + b2f(a1.z)) + w1 * (b2f(b0.z) + b2f(b1.z));
  o.w = w0 * (b2f(a0.w) + b2f(a1.w)) + w1 * (b2f(b0.w) + b2f(b1.w));
  *(float4*)(out + (size_t)t * H_DIM + c) = o;
}

// =================== fallback path (round-1-proven kernels) ================
__global__ __launch_bounds__(256) void router_fb(
    const float* __restrict__ x, const float* __restrict__ gate,
    float* __restrict__ logits_out, __hip_bfloat16* __restrict__ xb,
    int* __restrict__ counts, int* __restrict__ idx_list,
    float* __restrict__ wgt_list)
{
  const int wv = threadIdx.x >> 6;
  const int lane = threadIdx.x & 63;
  const int t = blockIdx.x * 4 + wv;
  const float4* xr = (const float4*)(x + (size_t)t * H_DIM);
  const float4* g4 = (const float4*)gate;
  float acc[E_NUM];
#pragma unroll
  for (int e = 0; e < E_NUM; ++e) acc[e] = 0.f;
  unsigned* xbo = (unsigned*)(xb + (size_t)t * H_DIM);
#pragma unroll
  for (int j = 0; j < 4; ++j) {
    int i = j * 64 + lane;
    float4 xv = xr[i];
    uint2 pk;
    pk.x = pack2bf16(xv.x, xv.y);
    pk.y = pack2bf16(xv.z, xv.w);
    *(uint2*)(xbo + i * 2) = pk;
#pragma unroll
    for (int e = 0; e < E_NUM; ++e) {
      float4 gv = g4[e * 256 + i];
      acc[e] += xv.x * gv.x + xv.y * gv.y + xv.z * gv.z + xv.w * gv.w;
    }
  }
#pragma unroll
  for (int off = 32; off > 0; off >>= 1) {
#pragma unroll
    for (int e = 0; e < E_NUM; ++e) acc[e] += __shfl_xor(acc[e], off, 64);
  }
  if (lane == 0) {
#pragma unroll
    for (int e = 0; e < E_NUM; ++e) logits_out[(size_t)t * E_NUM + e] = acc[e];
    int i0 = 0; float v0 = acc[0];
#pragma unroll
    for (int e = 1; e < E_NUM; ++e) if (acc[e] > v0) { v0 = acc[e]; i0 = e; }
    int i1 = -1; float v1 = -1e30f;
#pragma unroll
    for (int e = 0; e < E_NUM; ++e)
      if (e != i0 && acc[e] > v1) { v1 = acc[e]; i1 = e; }
    float p1 = __expf(v1 - v0);
    float w0 = 1.f / (1.f + p1);
    float w1 = p1 / (1.f + p1);
    int pos0 = atomicAdd(&counts[i0], 1);
    idx_list[i0 * T_TOK + pos0] = t;
    wgt_list[i0 * T_TOK + pos0] = w0;
    int pos1 = atomicAdd(&counts[i1], 1);
    idx_list[i1 * T_TOK + pos1] = t;
    wgt_list[i1 * T_TOK + pos1] = w1;
  }
}

__global__ __launch_bounds__(256) void gemm1_fb(
    const __hip_bfloat16* __restrict__ xb,
    const float* __restrict__ w1, const float* __restrict__ w3,
    const int* __restrict__ counts, const int* __restrict__ idx_list,
    __hip_bfloat16* __restrict__ hidden)
{
  const int e = blockIdx.z;
  const int n_e = counts[e];
  const int tm = blockIdx.y;
  if (n_e == 0 || tm * 128 >= n_e) return;
  const int tn = blockIdx.x;
  const int f0 = tn * 128;
  const int off_e = prefix_off(counts, e);

  __shared__ short sA[128 * 64];
  __shared__ short sB1[128 * 64];
  __shared__ short sB3[128 * 64];
  __shared__ int s_row[128];

  const int tid = threadIdx.x;
  if (tid < 128) {
    int pos = tm * 128 + tid;
    int p = pos < n_e ? pos : n_e - 1;
    s_row[tid] = idx_list[e * T_TOK + p];
  }
  const int lane = tid & 63;
  const int wv = tid >> 6;
  const int wrow = (wv >> 1) * 64;
  const int wcol = (wv & 1) * 64;
  const int cc = tid & 7;
  const int rbase = tid >> 3;

  floatx4 acc1[4][4], acc3[4][4];
#pragma unroll
  for (int m = 0; m < 4; ++m)
#pragma unroll
    for (int n = 0; n < 4; ++n)
#pragma unroll
      for (int q = 0; q < 4; ++q) { acc1[m][n][q] = 0.f; acc3[m][n][q] = 0.f; }

  const float* w1e = w1 + (size_t)e * F_DIM * H_DIM + (size_t)f0 * H_DIM;
  const float* w3e = w3 + (size_t)e * F_DIM * H_DIM + (size_t)f0 * H_DIM;

  for (int kt = 0; kt < H_DIM / 64; ++kt) {
    const int k0 = kt * 64;
    __syncthreads();
#pragma unroll
    for (int i = 0; i < 4; ++i) {
      int rr = rbase + 32 * i;
      uint4 av = *(const uint4*)(xb + (size_t)s_row[rr] * H_DIM + k0 + cc * 8);
      *(uint4*)((char*)sA + swz(rr, cc * 16)) = av;
      const float4* p1 = (const float4*)(w1e + (size_t)rr * H_DIM + k0 + cc * 8);
      float4 a1 = p1[0], b1 = p1[1];
      uint4 pb1;
      pb1.x = pack2bf16(a1.x, a1.y); pb1.y = pack2bf16(a1.z, a1.w);
      pb1.z = pack2bf16(b1.x, b1.y); pb1.w = pack2bf16(b1.z, b1.w);
      *(uint4*)((char*)sB1 + swz(rr, cc * 16)) = pb1;
      const float4* p3 = (const float4*)(w3e + (size_t)rr * H_DIM + k0 + cc * 8);
      float4 a3 = p3[0], b3 = p3[1];
      uint4 pb3;
      pb3.x = pack2bf16(a3.x, a3.y); pb3.y = pack2bf16(a3.z, a3.w);
      pb3.z = pack2bf16(b3.x, b3.y); pb3.w = pack2bf16(b3.z, b3.w);
      *(uint4*)((char*)sB3 + swz(rr, cc * 16)) = pb3;
    }
    __syncthreads();
#pragma unroll
    for (int kk = 0; kk < 2; ++kk) {
      const int colb = kk * 64 + (lane >> 4) * 16;
      bf16x8 af[4], bf1[4], bf3[4];
#pragma unroll
      for (int m = 0; m < 4; ++m)
        af[m] = *(const bf16x8*)((const char*)sA +
                                 swz(wrow + m * 16 + (lane & 15), colb));
#pragma unroll
      for (int n = 0; n < 4; ++n) {
        bf1[n] = *(const bf16x8*)((const char*)sB1 +
                                  swz(wcol + n * 16 + (lane & 15), colb));
        bf3[n] = *(const bf16x8*)((const char*)sB3 +
                                  swz(wcol + n * 16 + (lane & 15), colb));
      }
#pragma unroll
      for (int m = 0; m < 4; ++m)
#pragma unroll
        for (int n = 0; n < 4; ++n) {
          acc1[m][n] = __builtin_amdgcn_mfma_f32_16x16x32_bf16(
              af[m], bf1[n], acc1[m][n], 0, 0, 0);
          acc3[m][n] = __builtin_amdgcn_mfma_f32_16x16x32_bf16(
              af[m], bf3[n], acc3[m][n], 0, 0, 0);
        }
    }
  }
#pragma unroll
  for (int m = 0; m < 4; ++m) {
#pragma unroll
    for (int q = 0; q < 4; ++q) {
      int rl = wrow + m * 16 + ((lane >> 4) << 2) + q;
      int pos = tm * 128 + rl;
      if (pos < n_e) {
        __hip_bfloat16* hrow = hidden + (size_t)(off_e + pos) * F_DIM + f0;
#pragma unroll
        for (int n = 0; n < 4; ++n) {
          float h1 = acc1[m][n][q];
          float h3 = acc3[m][n][q];
          float h = (h1 / (1.f + __expf(-h1))) * h3;
          hrow[wcol + n * 16 + (lane & 15)] = __float2bfloat16(h);
        }
      }
    }
  }
}

__global__ __launch_bounds__(256) void gemm2_fb(
    const __hip_bfloat16* __restrict__ hidden, const float* __restrict__ w2,
    const int* __restrict__ counts, const int* __restrict__ idx_list,
    const float* __restrict__ wgt_list, float* __restrict__ out)
{
  const int e = blockIdx.z;
  const int n_e = counts[e];
  const int tm = blockIdx.y;
  if (n_e == 0 || tm * 128 >= n_e) return;
  const int tn = blockIdx.x;
  const int n0 = tn * 128;
  const int off_e = prefix_off(counts, e);

  __shared__ short sA[128 * 64];
  __shared__ short sB[128 * 64];
  __shared__ int s_tok[128];
  __shared__ float s_wgt[128];

  const int tid = threadIdx.x;
  if (tid < 128) {
    int pos = tm * 128 + tid;
    if (pos < n_e) {
      s_tok[tid] = idx_list[e * T_TOK + pos];
      s_wgt[tid] = wgt_list[e * T_TOK + pos];
    } else {
      s_tok[tid] = -1;
      s_wgt[tid] = 0.f;
    }
  }
  const int lane = tid & 63;
  const int wv = tid >> 6;
  const int wrow = (wv >> 1) * 64;
  const int wcol = (wv & 1) * 64;
  const int cc = tid & 7;
  const int rbase = tid >> 3;

  floatx4 acc[4][4];
#pragma unroll
  for (int m = 0; m < 4; ++m)
#pragma unroll
    for (int n = 0; n < 4; ++n)
#pragma unroll
      for (int q = 0; q < 4; ++q) acc[m][n][q] = 0.f;

  const float* w2e = w2 + (size_t)e * H_DIM * F_DIM + (size_t)n0 * F_DIM;

  for (int kt = 0; kt < F_DIM / 64; ++kt) {
    const int k0 = kt * 64;
    __syncthreads();
#pragma unroll
    for (int i = 0; i < 4; ++i) {
      int rr = rbase + 32 * i;
      int pos = tm * 128 + rr;
      int pr = pos < n_e ? pos : n_e - 1;
      uint4 av = *(const uint4*)(hidden + (size_t)(off_e + pr) * F_DIM +
                                 k0 + cc * 8);
      *(uint4*)((char*)sA + swz(rr, cc * 16)) = av;
      const float4* pb = (const float4*)(w2e + (size_t)rr * F_DIM + k0 + cc * 8);
      float4 ba = pb[0], bb = pb[1];
      uint4 pk;
      pk.x = pack2bf16(ba.x, ba.y); pk.y = pack2bf16(ba.z, ba.w);
      pk.z = pack2bf16(bb.x, bb.y); pk.w = pack2bf16(bb.z, bb.w);
      *(uint4*)((char*)sB + swz(rr, cc * 16)) = pk;
    }
    __syncthreads();
#pragma unroll
    for (int kk = 0; kk < 2; ++kk) {
      const int colb = kk * 64 + (lane >> 4) * 16;
      bf16x8 af[4], bf[4];
#pragma unroll
      for (int m = 0; m < 4; ++m)
        af[m] = *(const bf16x8*)((const char*)sA +
                                 swz(wrow + m * 16 + (lane & 15), colb));
#pragma unroll
      for (int n = 0; n < 4; ++n)
        bf[n] = *(const bf16x8*)((const char*)sB +
                                 swz(wcol + n * 16 + (lane & 15), colb));
#pragma unroll
      for (int m = 0; m < 4; ++m)
#pragma unroll
        for (int n = 0; n < 4; ++n)
          acc[m][n] = __builtin_amdgcn_mfma_f32_16x16x32_bf16(
              af[m], bf[n], acc[m][n], 0, 0, 0);
    }
  }
#pragma unroll
  for (int m = 0; m < 4; ++m) {
#pragma unroll
    for (int q = 0; q < 4; ++q) {
      int rl = wrow + m * 16 + ((lane >> 4) << 2) + q;
      int tok = s_tok[rl];
      if (tok >= 0) {
        float wgt = s_wgt[rl];
        float* orow = out + (size_t)tok * H_DIM + n0;
#pragma unroll
        for (int n = 0; n < 4; ++n)
          atomicAdd(&orow[wcol + n * 16 + (lane & 15)], wgt * acc[m][n][q]);
      }
    }
  }
}

extern "C" void kernel_launch(void* const* d_in, const int* in_sizes, int n_in,
                              void* d_out, int out_size, void* d_ws,
                              size_t ws_size, hipStream_t stream) {
  const float* x = (const float*)d_in[0];
  const float* gate = (const float*)d_in[1];
  const float* w1 = (const float*)d_in[2];
  const float* w3 = (const float*)d_in[3];
  const float* w2 = (const float*)d_in[4];

  float* out = (float*)d_out;                        // [T, H]
  float* logits = out + (size_t)T_TOK * H_DIM;       // [T, E]

  char* ws = (char*)d_ws;
  const size_t o_idx = 256;
  const size_t o_wgt = o_idx + (size_t)E_NUM * T_TOK * 4;
  const size_t o_m0  = o_wgt + (size_t)E_NUM * T_TOK * 4;
  const size_t o_m1  = o_m0 + (size_t)T_TOK * 4;
  const size_t o_wc  = o_m1 + (size_t)T_TOK * 4;
  const size_t o_xb  = o_wc + (size_t)T_TOK * 4;
  const size_t o_hid = o_xb + (size_t)T_TOK * H_DIM * 2;
  const size_t o_wB  = o_hid + (size_t)2 * T_TOK * F_DIM * 2;
  const size_t o_w2b = o_wB + (size_t)E_NUM * 2 * F_DIM * H_DIM * 2;
  const size_t need  = o_w2b + (size_t)E_NUM * H_DIM * F_DIM * 2;  // ~184 MiB

  int* counts = (int*)ws;
  int* idx_list = (int*)(ws + o_idx);
  float* wgt_list = (float*)(ws + o_wgt);
  int* meta0 = (int*)(ws + o_m0);
  int* meta1 = (int*)(ws + o_m1);
  float* wcomb = (float*)(ws + o_wc);
  __hip_bfloat16* xb = (__hip_bfloat16*)(ws + o_xb);
  __hip_bfloat16* hidden = (__hip_bfloat16*)(ws + o_hid);

  hipMemsetAsync(counts, 0, 64, stream);

  if (ws_size >= need) {
    __hip_bfloat16* wB = (__hip_bfloat16*)(ws + o_wB);
    __hip_bfloat16* w2b = (__hip_bfloat16*)(ws + o_w2b);
    __hip_bfloat16* y = (__hip_bfloat16*)(ws + o_wB);   // alias: wB dead then
                                                        // (2 halves = 34 MB)

    prep_kernel<<<NB_W13 + NB_W2 + NB_RT, 256, 0, stream>>>(
        w1, w3, w2, x, gate, wB, w2b, logits, xb, counts, idx_list, wgt_list,
        meta0, meta1, wcomb);
    gemm1_kernel<<<dim3(2 * F_DIM / 256, T_TOK / 256, E_NUM), 512, 0,
                   stream>>>(xb, wB, counts, idx_list, hidden);
    gemm2_kernel<<<dim3(8, 32, 2 * E_NUM), 256, 0, stream>>>(
        hidden, w2b, counts, y);
    combine_kernel<<<T_TOK, 256, 0, stream>>>(y, counts, meta0, meta1, wcomb,
                                              out);
  } else {
    hipMemsetAsync(out, 0, (size_t)T_TOK * H_DIM * sizeof(float), stream);
    router_fb<<<T_TOK / 4, 256, 0, stream>>>(x, gate, logits, xb, counts,
                                             idx_list, wgt_list);
    gemm1_fb<<<dim3(F_DIM / 128, T_TOK / 128, E_NUM), 256, 0, stream>>>(
        xb, w1, w3, counts, idx_list, hidden);
    gemm2_fb<<<dim3(H_DIM / 128, T_TOK / 128, E_NUM), 256, 0, stream>>>(
        hidden, w2, counts, idx_list, wgt_list, out);
  }
}